// Round 1
// baseline (1266.811 us; speedup 1.0000x reference)
//
#include <hip/hip_runtime.h>

// ---------------------------------------------------------------------------
// GroupedQueryAttention: int8 dynamic-quant QKV proj + RoPE + causal GQA + O proj
// B=2 S=1024 D=4096 H=32 KV=8 HD=128 GROUP=4
//
// Pipeline (all bf16 MFMA GEMMs, C = A * B^T, fp32 accumulate):
//  K1 quantize_rows(x)            -> Xi (bf16-exact int8 vals), sx[2048]
//  K2 convert weights int32->bf16 -> Wqkv (6144x4096), Wo (4096x4096)
//  K3 gemm: Y = Xi * Wqkv^T       (2048x6144)
//  K4 dequant+bias+rope+pack      -> Q (B,H,S,HD) bf16, K (B,KV,S,HD) bf16,
//                                    V^T hi/lo (B,KV,HD,S) bf16
//  K5 per chunk of PC (b,h) pairs:
//       gemm: Sc = Q*K^T /sqrt(128)   (fp32 scores)
//       softmax (causal)          -> Phi,Plo bf16 (hi/lo split)
//       gemm x3 accumulate: O = Phi*Vh + Phi*Vl + Plo*Vh   (B,S,H*HD fp32)
//  K6 quantize_rows(O)            -> Oi, sxo
//  K7 gemm: Yo = Oi * Wo^T
//  K8 out = Yo * sxo[row] * so[col]
// ---------------------------------------------------------------------------

#define B_   2
#define S_   1024
#define D_   4096
#define H_   32
#define KV_  8
#define HD_  128
#define NR   (B_ * S_)          // 2048 rows
#define NQKV (H_*HD_ + 2*KV_*HD_) // 6144

typedef __attribute__((ext_vector_type(8))) short  short8;
typedef __attribute__((ext_vector_type(4))) float  f32x4;

static __device__ __forceinline__ unsigned short f2bf(float f) {
    unsigned u = __builtin_bit_cast(unsigned, f);
    u += 0x7fffu + ((u >> 16) & 1u);     // round-to-nearest-even
    return (unsigned short)(u >> 16);
}
static __device__ __forceinline__ float bf2f(unsigned short h) {
    unsigned u = ((unsigned)h) << 16;
    return __builtin_bit_cast(float, u);
}

// --------------------------- K1/K6: row quantization ------------------------
// Replicates reference: sx = max|row|/127 (1.0 if 0); xi = clip(rint(x/sx),±127)
__global__ __launch_bounds__(256) void quantize_rows_k(
    const float* __restrict__ X, unsigned short* __restrict__ Xq,
    float* __restrict__ sx_out, int K)
{
    int row = blockIdx.x;
    const float* xr = X + (size_t)row * K;
    int t = threadIdx.x;
    float m = 0.f;
    for (int j = t; j < K; j += 256) m = fmaxf(m, fabsf(xr[j]));
    for (int off = 32; off > 0; off >>= 1) m = fmaxf(m, __shfl_down(m, off, 64));
    __shared__ float red[4];
    if ((t & 63) == 0) red[t >> 6] = m;
    __syncthreads();
    float mm = fmaxf(fmaxf(red[0], red[1]), fmaxf(red[2], red[3]));
    float sx = mm / 127.0f;
    if (sx == 0.f) sx = 1.f;
    if (t == 0) sx_out[row] = sx;
    for (int j = t; j < K; j += 256) {
        float v = rintf(xr[j] / sx);
        v = fminf(fmaxf(v, -127.f), 127.f);
        Xq[(size_t)row * K + j] = f2bf(v);   // exact: |v|<=127 integer
    }
}

// --------------------------- K2: weight convert -----------------------------
__global__ __launch_bounds__(256) void convert_w_k(
    const int* __restrict__ W, unsigned short* __restrict__ Wb, int n)
{
    int stride = gridDim.x * 256;
    for (int i = blockIdx.x * 256 + threadIdx.x; i < n; i += stride)
        Wb[i] = f2bf((float)W[i]);           // exact: |w|<=127
}

// --------------------------- GEMM: C = A * B^T (bf16 -> fp32) ---------------
// A: M x K bf16 row-major, Bm: N x K bf16 row-major, C: M x (ldc) fp32.
// MODE 0: plain.  MODE 1: QK^T batch.  MODE 2: PV batch (C strided into O).
#define BM 128
#define BN 128
#define BK 32

template<int MODE>
__global__ __launch_bounds__(256) void gemm_bt_k(
    const unsigned short* __restrict__ Aall,
    const unsigned short* __restrict__ Ball,
    float* __restrict__ Call,
    int M, int N, int K, int ldc, float alpha, int accum, int zbase)
{
    const unsigned short* A  = Aall;
    const unsigned short* Bm = Ball;
    float* C = Call;
    if (MODE == 1) {
        int zg = zbase + blockIdx.z;                 // (b,h) pair
        A  += (size_t)zg * (S_ * HD_);               // Q pair base
        Bm += (size_t)(zg >> 2) * (S_ * HD_);        // K kv-head base
        C  += (size_t)blockIdx.z * (S_ * S_);        // Sc chunk-local
    } else if (MODE == 2) {
        int zg = zbase + blockIdx.z;
        A  += (size_t)blockIdx.z * (S_ * S_);        // P chunk-local
        Bm += (size_t)(zg >> 2) * (HD_ * S_);        // V^T kv-head base
        C  += (size_t)(zg >> 5) * ((size_t)S_ * (H_*HD_)) + (size_t)(zg & 31) * HD_;
    }

    __shared__ __align__(16) unsigned short As[BM * BK];
    __shared__ __align__(16) unsigned short Bs[BN * BK];

    int t    = threadIdx.x;
    int m0   = blockIdx.y * BM;
    int n0   = blockIdx.x * BN;
    int lane = t & 63;
    int w    = t >> 6;
    int wm   = (w >> 1) * 64;
    int wn   = (w & 1) * 64;
    int l15  = lane & 15;
    int quad = lane >> 4;

    f32x4 acc[4][4];
    #pragma unroll
    for (int i = 0; i < 4; i++)
        #pragma unroll
        for (int j = 0; j < 4; j++) { f32x4 z = {0.f,0.f,0.f,0.f}; acc[i][j] = z; }

    int srow = t >> 2;            // 0..63
    int scol = (t & 3) * 8;       // 0,8,16,24

    for (int k0 = 0; k0 < K; k0 += BK) {
        const unsigned short* ga = A  + (size_t)(m0 + srow) * K + k0 + scol;
        const unsigned short* gb = Bm + (size_t)(n0 + srow) * K + k0 + scol;
        *(short8*)&As[srow * BK + scol]        = *(const short8*)ga;
        *(short8*)&As[(srow + 64) * BK + scol] = *(const short8*)(ga + (size_t)64 * K);
        *(short8*)&Bs[srow * BK + scol]        = *(const short8*)gb;
        *(short8*)&Bs[(srow + 64) * BK + scol] = *(const short8*)(gb + (size_t)64 * K);
        __syncthreads();

        short8 af[4], bf[4];
        #pragma unroll
        for (int i = 0; i < 4; i++) {
            af[i] = *(const short8*)&As[(wm + i*16 + l15) * BK + quad * 8];
            bf[i] = *(const short8*)&Bs[(wn + i*16 + l15) * BK + quad * 8];
        }
        #pragma unroll
        for (int i = 0; i < 4; i++)
            #pragma unroll
            for (int j = 0; j < 4; j++)
                acc[i][j] = __builtin_amdgcn_mfma_f32_16x16x32_bf16(af[i], bf[j], acc[i][j], 0, 0, 0);
        __syncthreads();
    }

    #pragma unroll
    for (int i = 0; i < 4; i++) {
        #pragma unroll
        for (int j = 0; j < 4; j++) {
            #pragma unroll
            for (int r = 0; r < 4; r++) {
                int row = m0 + wm + i*16 + quad*4 + r;
                int col = n0 + wn + j*16 + l15;
                size_t idx = (size_t)row * ldc + col;
                float prev = accum ? C[idx] : 0.f;
                C[idx] = prev + acc[i][j][r] * alpha;
            }
        }
    }
}

// --------------------------- K4: dequant + bias + rope + pack ---------------
__global__ __launch_bounds__(256) void derope_k(
    const float* __restrict__ Y, const float* __restrict__ sx,
    const float* __restrict__ sq, const float* __restrict__ bq,
    const float* __restrict__ sk, const float* __restrict__ bk,
    const float* __restrict__ sv, const float* __restrict__ bv,
    const float* __restrict__ cosb, const float* __restrict__ sinb,
    unsigned short* __restrict__ Q, unsigned short* __restrict__ Kb,
    unsigned short* __restrict__ Vh, unsigned short* __restrict__ Vl)
{
    int r = blockIdx.x;               // (b,s)
    int b = r >> 10;
    int s = r & (S_ - 1);
    float sxr = sx[r];
    const float* yr = Y + (size_t)r * NQKV;
    int t = threadIdx.x;

    // Q: 32 heads x 64 rotation pairs
    for (int p = t; p < H_ * 64; p += 256) {
        int h = p >> 6, d = p & 63;
        int ca = h * HD_ + d;
        float a  = yr[ca]      * sxr * sq[ca]      + bq[ca];
        float b2 = yr[ca + 64] * sxr * sq[ca + 64] + bq[ca + 64];
        float c  = cosb[s * HD_ + d], sn = sinb[s * HD_ + d];
        size_t base = (((size_t)(b * H_ + h)) * S_ + s) * HD_;
        Q[base + d]      = f2bf(a * c - b2 * sn);
        Q[base + d + 64] = f2bf(b2 * c + a * sn);
    }
    // K: 8 kv heads x 64 pairs
    for (int p = t; p < KV_ * 64; p += 256) {
        int kv = p >> 6, d = p & 63;
        int ci = kv * HD_ + d;
        int ca = H_ * HD_ + ci;
        float a  = yr[ca]      * sxr * sk[ci]      + bk[ci];
        float b2 = yr[ca + 64] * sxr * sk[ci + 64] + bk[ci + 64];
        float c  = cosb[s * HD_ + d], sn = sinb[s * HD_ + d];
        size_t base = (((size_t)(b * KV_ + kv)) * S_ + s) * HD_;
        Kb[base + d]      = f2bf(a * c - b2 * sn);
        Kb[base + d + 64] = f2bf(b2 * c + a * sn);
    }
    // V: 8 kv heads x 128 dims -> transposed (B,KV,HD,S), hi/lo split
    for (int p = t; p < KV_ * HD_; p += 256) {
        int kv = p >> 7, d = p & 127;
        int ci = kv * HD_ + d;
        int ca = H_ * HD_ + KV_ * HD_ + ci;
        float v = yr[ca] * sxr * sv[ci] + bv[ci];
        unsigned short vh = f2bf(v);
        float vrem = v - bf2f(vh);
        size_t idx = (((size_t)(b * KV_ + kv)) * HD_ + d) * S_ + s;
        Vh[idx] = vh;
        Vl[idx] = f2bf(vrem);
    }
}

// --------------------------- K5b: causal softmax ----------------------------
__global__ __launch_bounds__(256) void softmax_k(
    const float* __restrict__ Sc, unsigned short* __restrict__ Phi,
    unsigned short* __restrict__ Plo)
{
    int q = blockIdx.x;
    int z = blockIdx.y;                       // chunk-local pair
    const float* sr = Sc + ((size_t)z * S_ + q) * S_;
    unsigned short* ph = Phi + ((size_t)z * S_ + q) * S_;
    unsigned short* pl = Plo + ((size_t)z * S_ + q) * S_;
    int t = threadIdx.x;
    int nk = q + 1;

    float m = -1e30f;
    for (int k = t; k < nk; k += 256) m = fmaxf(m, sr[k]);
    for (int off = 32; off > 0; off >>= 1) m = fmaxf(m, __shfl_down(m, off, 64));
    __shared__ float red[4];
    __shared__ float bmax, bsum;
    if ((t & 63) == 0) red[t >> 6] = m;
    __syncthreads();
    if (t == 0) bmax = fmaxf(fmaxf(red[0], red[1]), fmaxf(red[2], red[3]));
    __syncthreads();
    m = bmax;

    float sum = 0.f;
    for (int k = t; k < nk; k += 256) sum += expf(sr[k] - m);
    for (int off = 32; off > 0; off >>= 1) sum += __shfl_down(sum, off, 64);
    if ((t & 63) == 0) red[t >> 6] = sum;
    __syncthreads();
    if (t == 0) bsum = red[0] + red[1] + red[2] + red[3];
    __syncthreads();
    float inv = 1.0f / bsum;

    for (int k = t; k < S_; k += 256) {
        if (k < nk) {
            float p = expf(sr[k] - m) * inv;
            unsigned short hp = f2bf(p);
            ph[k] = hp;
            pl[k] = f2bf(p - bf2f(hp));
        } else {
            ph[k] = 0; pl[k] = 0;
        }
    }
}

// --------------------------- K8: final dequant ------------------------------
__global__ __launch_bounds__(256) void finout_k(
    const float* __restrict__ Yo, const float* __restrict__ sxo,
    const float* __restrict__ so, float* __restrict__ out)
{
    int i = blockIdx.x * 256 + threadIdx.x;   // 0 .. 2048*4096-1
    int r = i >> 12;
    int c = i & 4095;
    out[i] = Yo[i] * sxo[r] * so[c];
}

// ---------------------------------------------------------------------------
extern "C" void kernel_launch(void* const* d_in, const int* in_sizes, int n_in,
                              void* d_out, int out_size, void* d_ws, size_t ws_size,
                              hipStream_t stream)
{
    (void)in_sizes; (void)n_in; (void)out_size;
    const float* x    = (const float*)d_in[0];
    const float* cosb = (const float*)d_in[1];
    const float* sinb = (const float*)d_in[2];
    const int*   wq   = (const int*)d_in[3];
    const float* sq   = (const float*)d_in[4];
    const float* bq   = (const float*)d_in[5];
    const int*   wk   = (const int*)d_in[6];
    const float* sk   = (const float*)d_in[7];
    const float* bk   = (const float*)d_in[8];
    const int*   wv   = (const int*)d_in[9];
    const float* sv   = (const float*)d_in[10];
    const float* bv   = (const float*)d_in[11];
    const int*   wo   = (const int*)d_in[12];
    const float* so   = (const float*)d_in[13];
    float* out = (float*)d_out;
    char*  ws  = (char*)d_ws;

    // Attention processed in chunks of PC (b,h) pairs to bound scratch.
    // PC=32 needs ~382 MB ws; PC=16 needs ~248 MB.
    int PC = (ws_size >= 381714432ull) ? 32 : 16;
    size_t ScB = (size_t)PC * S_ * S_ * 4;   // fp32 scores chunk
    size_t PB  = (size_t)PC * S_ * S_ * 2;   // bf16 probs chunk (x2: hi+lo)

    size_t R1sz = (ScB > 67108864ull) ? ScB : 67108864ull;        // Xi+Y | Sc
    size_t R2sz = (2*PB > 50331648ull) ? 2*PB : 50331648ull;      // Wqkv | Phi+Plo | Oi
    size_t R1 = 0;
    size_t R2 = R1 + R1sz;
    size_t R3 = R2 + R2sz;            // Wo (33.5 MB)
    size_t R4 = R3 + 33554432ull;     // Q bf16 | Yo fp32 (33.5 MB)
    size_t R5 = R4 + 33554432ull;     // K bf16 (4.2 MB)
    size_t R6 = R5 + 4194304ull;      // V^T hi+lo (8.4 MB)
    size_t R7 = R6 + 8388608ull;      // O fp32 (33.5 MB)
    size_t R8 = R7 + 33554432ull;     // sx, sxo

    unsigned short* Xi   = (unsigned short*)(ws + R1);
    float*          Y    = (float*)(ws + R1 + 16777216ull);
    float*          Sc   = (float*)(ws + R1);
    unsigned short* Wqkv = (unsigned short*)(ws + R2);
    unsigned short* Phi  = (unsigned short*)(ws + R2);
    unsigned short* Plo  = (unsigned short*)(ws + R2 + PB);
    unsigned short* Oi   = (unsigned short*)(ws + R2);
    unsigned short* Wo   = (unsigned short*)(ws + R3);
    unsigned short* Q    = (unsigned short*)(ws + R4);
    float*          Yo   = (float*)(ws + R4);
    unsigned short* Kb   = (unsigned short*)(ws + R5);
    unsigned short* Vh   = (unsigned short*)(ws + R6);
    unsigned short* Vl   = (unsigned short*)(ws + R6 + 4194304ull);
    float*          O    = (float*)(ws + R7);
    float*          sx   = (float*)(ws + R8);
    float*          sxo  = (float*)(ws + R8 + 8192);

    // K1: quantize x rows
    quantize_rows_k<<<dim3(NR), dim3(256), 0, stream>>>(x, Xi, sx, D_);

    // K2: weights -> bf16 (Wqkv rows: [wq(4096); wk(1024); wv(1024)])
    convert_w_k<<<dim3(4096), dim3(256), 0, stream>>>(wq, Wqkv,            4096*4096);
    convert_w_k<<<dim3(1024), dim3(256), 0, stream>>>(wk, Wqkv + 16777216, 1024*4096);
    convert_w_k<<<dim3(1024), dim3(256), 0, stream>>>(wv, Wqkv + 20971520, 1024*4096);
    convert_w_k<<<dim3(4096), dim3(256), 0, stream>>>(wo, Wo,              4096*4096);

    // K3: Y = Xi * Wqkv^T   (2048 x 6144, K=4096)
    gemm_bt_k<0><<<dim3(48,16,1), dim3(256), 0, stream>>>(
        Xi, Wqkv, Y, NR, NQKV, D_, NQKV, 1.0f, 0, 0);

    // K4: dequant + rope + pack
    derope_k<<<dim3(NR), dim3(256), 0, stream>>>(
        Y, sx, sq, bq, sk, bk, sv, bv, cosb, sinb, Q, Kb, Vh, Vl);

    // K5: attention in chunks
    const float inv_sqrt_hd = 0.08838834764831845f;   // 1/sqrt(128)
    int nch = 64 / PC;
    for (int c = 0; c < nch; ++c) {
        int zb = c * PC;
        gemm_bt_k<1><<<dim3(8,8,PC), dim3(256), 0, stream>>>(
            Q, Kb, Sc, S_, S_, HD_, S_, inv_sqrt_hd, 0, zb);
        softmax_k<<<dim3(S_, PC), dim3(256), 0, stream>>>(Sc, Phi, Plo);
        gemm_bt_k<2><<<dim3(1,8,PC), dim3(256), 0, stream>>>(
            Phi, Vh, O, S_, HD_, S_, H_*HD_, 1.0f, 0, zb);
        gemm_bt_k<2><<<dim3(1,8,PC), dim3(256), 0, stream>>>(
            Phi, Vl, O, S_, HD_, S_, H_*HD_, 1.0f, 1, zb);
        gemm_bt_k<2><<<dim3(1,8,PC), dim3(256), 0, stream>>>(
            Plo, Vh, O, S_, HD_, S_, H_*HD_, 1.0f, 1, zb);
    }

    // K6: quantize attention output rows
    quantize_rows_k<<<dim3(NR), dim3(256), 0, stream>>>(O, Oi, sxo, H_*HD_);

    // K7: Yo = Oi * Wo^T
    gemm_bt_k<0><<<dim3(32,16,1), dim3(256), 0, stream>>>(
        Oi, Wo, Yo, NR, D_, H_*HD_ * H_ / H_ * 0 + 4096, D_, 1.0f, 0, 0);

    // K8: final dequant
    finout_k<<<dim3(32768), dim3(256), 0, stream>>>(Yo, sxo, so, out);
}

// Round 3
// 808.395 us; speedup vs baseline: 1.5671x; 1.5671x over previous
//
#include <hip/hip_runtime.h>

// ---------------------------------------------------------------------------
// GroupedQueryAttention: int8 dynamic-quant QKV proj + RoPE + causal GQA + O proj
// B=2 S=1024 D=4096 H=32 KV=8 HD=128 GROUP=4
//
// R3 = R2 design with the convert_w_k grid bug fixed (R2 only converted 1/4
// of each weight matrix). global_load_lds staging in all GEMMs, causal block
// skip in QK^T, in-place bf16 softmax, dual-B PV kernel, fused O-proj epilogue.
// ---------------------------------------------------------------------------

#define B_   2
#define S_   1024
#define D_   4096
#define H_   32
#define KV_  8
#define HD_  128
#define NR   (B_ * S_)            // 2048 rows
#define NQKV (H_*HD_ + 2*KV_*HD_) // 6144

typedef __attribute__((ext_vector_type(8))) short  short8;
typedef __attribute__((ext_vector_type(4))) float  f32x4;
typedef __attribute__((ext_vector_type(4))) int    int4v;
typedef __attribute__((ext_vector_type(4))) unsigned short ushort4v;

static __device__ __forceinline__ unsigned short f2bf(float f) {
    unsigned u = __builtin_bit_cast(unsigned, f);
    u += 0x7fffu + ((u >> 16) & 1u);     // round-to-nearest-even
    return (unsigned short)(u >> 16);
}
static __device__ __forceinline__ float bf2f(unsigned short h) {
    unsigned u = ((unsigned)h) << 16;
    return __builtin_bit_cast(float, u);
}

// async global->LDS, 16 B per lane. LDS dest = wave-uniform base + lane*16.
static __device__ __forceinline__ void async_cp16(const unsigned short* g, unsigned short* l) {
    __builtin_amdgcn_global_load_lds(
        (const __attribute__((address_space(1))) void*)g,
        (__attribute__((address_space(3))) void*)l, 16, 0, 0);
}

// --------------------------- K1/K6: row quantization ------------------------
__global__ __launch_bounds__(256) void quantize_rows_k(
    const float* __restrict__ X, unsigned short* __restrict__ Xq,
    float* __restrict__ sx_out, int K)
{
    int row = blockIdx.x;
    const float* xr = X + (size_t)row * K;
    int t = threadIdx.x;
    float m = 0.f;
    for (int j = t; j < K; j += 256) m = fmaxf(m, fabsf(xr[j]));
    for (int off = 32; off > 0; off >>= 1) m = fmaxf(m, __shfl_down(m, off, 64));
    __shared__ float red[4];
    if ((t & 63) == 0) red[t >> 6] = m;
    __syncthreads();
    float mm = fmaxf(fmaxf(red[0], red[1]), fmaxf(red[2], red[3]));
    float sx = mm / 127.0f;
    if (sx == 0.f) sx = 1.f;
    if (t == 0) sx_out[row] = sx;
    for (int j = t; j < K; j += 256) {
        float v = rintf(xr[j] / sx);
        v = fminf(fmaxf(v, -127.f), 127.f);
        Xq[(size_t)row * K + j] = f2bf(v);   // exact: |v|<=127 integer
    }
}

// --------------------------- K2: weight convert (int32 -> bf16) -------------
__global__ __launch_bounds__(256) void convert_w_k(
    const int* __restrict__ W, unsigned short* __restrict__ Wb, int n4)
{
    int i = blockIdx.x * 256 + threadIdx.x;   // one int4 per thread
    if (i >= n4) return;
    int4v w = *(const int4v*)(W + (size_t)i * 4);
    ushort4v o;
    o[0] = f2bf((float)w[0]); o[1] = f2bf((float)w[1]);
    o[2] = f2bf((float)w[2]); o[3] = f2bf((float)w[3]);
    *(ushort4v*)(Wb + (size_t)i * 4) = o;
}

// --------------------------- GEMM: C = A * B^T (bf16 -> fp32) ---------------
// MODE 0: plain (QKV proj).     MODE 1: QK^T batch, causal block skip.
// MODE 2: PV batch, dual-B (Vh+Vl), causal K-trim, C strided into O.
// MODE 3: O-proj, epilogue = acc * rs[row] * cs[col] -> out.
#define BM 128
#define BN 128
#define BK 32

template<int MODE>
__global__ __launch_bounds__(256) void gemm_bt_k(
    const unsigned short* __restrict__ Aall,
    const unsigned short* __restrict__ Ball,
    const unsigned short* __restrict__ B2all,
    float* __restrict__ Call,
    const float* __restrict__ rs, const float* __restrict__ cs,
    int M, int N, int K, int lda, int ldb, int ldc, int zbase)
{
    if (MODE == 1 && blockIdx.x > blockIdx.y) return;   // fully-masked block

    const unsigned short* A  = Aall;
    const unsigned short* Bm = Ball;
    const unsigned short* B2 = B2all;
    float* C = Call;
    if (MODE == 1) {
        int zg = zbase + blockIdx.z;                 // global (b,h) pair
        A  += (size_t)zg * (S_ * HD_);               // Q
        Bm += (size_t)(zg >> 2) * (S_ * HD_);        // K kv-head
        C  += (size_t)blockIdx.z * (S_ * S_);        // Sc chunk-local
    } else if (MODE == 2) {
        int zg = zbase + blockIdx.z;
        A  += (size_t)blockIdx.z * ((size_t)S_ * 2048);  // P in-place rows (stride 2048)
        Bm += (size_t)(zg >> 2) * (HD_ * S_);        // V^T hi
        B2 += (size_t)(zg >> 2) * (HD_ * S_);        // V^T lo
        C  += (size_t)(zg >> 5) * ((size_t)S_ * (H_*HD_)) + (size_t)(zg & 31) * HD_;
    }

    __shared__ __align__(16) unsigned short As[BM * BK];
    __shared__ __align__(16) unsigned short Bs[BN * BK];
    __shared__ __align__(16) unsigned short Bs2[(MODE == 2) ? BN * BK : 8];

    int t    = threadIdx.x;
    int m0   = blockIdx.y * BM;
    int n0   = blockIdx.x * BN;
    int lane = t & 63;
    int w    = t >> 6;
    int wm   = (w >> 1) * 64;
    int wn   = (w & 1) * 64;
    int l15  = lane & 15;
    int quad = lane >> 4;

    f32x4 acc[4][4];
    #pragma unroll
    for (int i = 0; i < 4; i++)
        #pragma unroll
        for (int j = 0; j < 4; j++) { f32x4 z = {0.f,0.f,0.f,0.f}; acc[i][j] = z; }

    int srow = t >> 2;            // 0..63
    int scol = (t & 3) * 8;       // 0,8,16,24
    unsigned short* lA0 = &As[w * 512];
    unsigned short* lA1 = &As[2048 + w * 512];
    unsigned short* lB0 = &Bs[w * 512];
    unsigned short* lB1 = &Bs[2048 + w * 512];
    unsigned short* lC0 = &Bs2[(MODE == 2) ? w * 512 : 0];
    unsigned short* lC1 = &Bs2[(MODE == 2) ? 2048 + w * 512 : 0];

    int kend = (MODE == 2) ? ((m0 + BM < K) ? m0 + BM : K) : K;   // causal trim

    for (int k0 = 0; k0 < kend; k0 += BK) {
        const unsigned short* ga = A  + (size_t)(m0 + srow) * lda + k0 + scol;
        const unsigned short* gb = Bm + (size_t)(n0 + srow) * ldb + k0 + scol;
        async_cp16(ga, lA0);
        async_cp16(ga + (size_t)64 * lda, lA1);
        async_cp16(gb, lB0);
        async_cp16(gb + (size_t)64 * ldb, lB1);
        if (MODE == 2) {
            const unsigned short* gb2 = B2 + (size_t)(n0 + srow) * ldb + k0 + scol;
            async_cp16(gb2, lC0);
            async_cp16(gb2 + (size_t)64 * ldb, lC1);
        }
        __syncthreads();

        short8 af[4], bf[4], bf2[4];
        #pragma unroll
        for (int i = 0; i < 4; i++) {
            af[i] = *(const short8*)&As[(wm + i*16 + l15) * BK + quad * 8];
            bf[i] = *(const short8*)&Bs[(wn + i*16 + l15) * BK + quad * 8];
            if (MODE == 2)
                bf2[i] = *(const short8*)&Bs2[(wn + i*16 + l15) * BK + quad * 8];
        }
        #pragma unroll
        for (int i = 0; i < 4; i++)
            #pragma unroll
            for (int j = 0; j < 4; j++) {
                acc[i][j] = __builtin_amdgcn_mfma_f32_16x16x32_bf16(af[i], bf[j], acc[i][j], 0, 0, 0);
                if (MODE == 2)
                    acc[i][j] = __builtin_amdgcn_mfma_f32_16x16x32_bf16(af[i], bf2[j], acc[i][j], 0, 0, 0);
            }
        __syncthreads();
    }

    #pragma unroll
    for (int i = 0; i < 4; i++) {
        #pragma unroll
        for (int j = 0; j < 4; j++) {
            #pragma unroll
            for (int r = 0; r < 4; r++) {
                int row = m0 + wm + i*16 + quad*4 + r;
                int col = n0 + wn + j*16 + l15;
                size_t idx = (size_t)row * ldc + col;
                float v = acc[i][j][r];
                if (MODE == 3) v *= rs[row] * cs[col];
                C[idx] = v;
            }
        }
    }
}

// --------------------------- K4: dequant + bias + rope + pack ---------------
__global__ __launch_bounds__(256) void derope_k(
    const float* __restrict__ Y, const float* __restrict__ sx,
    const float* __restrict__ sq, const float* __restrict__ bq,
    const float* __restrict__ sk, const float* __restrict__ bk,
    const float* __restrict__ sv, const float* __restrict__ bv,
    const float* __restrict__ cosb, const float* __restrict__ sinb,
    unsigned short* __restrict__ Q, unsigned short* __restrict__ Kb,
    unsigned short* __restrict__ Vh, unsigned short* __restrict__ Vl)
{
    const float qs = 0.08838834764831845f;   // 1/sqrt(HD) folded into Q
    int r = blockIdx.x;               // (b,s)
    int b = r >> 10;
    int s = r & (S_ - 1);
    float sxr = sx[r];
    const float* yr = Y + (size_t)r * NQKV;
    int t = threadIdx.x;

    for (int p = t; p < H_ * 64; p += 256) {
        int h = p >> 6, d = p & 63;
        int ca = h * HD_ + d;
        float a  = yr[ca]      * sxr * sq[ca]      + bq[ca];
        float b2 = yr[ca + 64] * sxr * sq[ca + 64] + bq[ca + 64];
        float c  = cosb[s * HD_ + d], sn = sinb[s * HD_ + d];
        size_t base = (((size_t)(b * H_ + h)) * S_ + s) * HD_;
        Q[base + d]      = f2bf((a * c - b2 * sn) * qs);
        Q[base + d + 64] = f2bf((b2 * c + a * sn) * qs);
    }
    for (int p = t; p < KV_ * 64; p += 256) {
        int kv = p >> 6, d = p & 63;
        int ci = kv * HD_ + d;
        int ca = H_ * HD_ + ci;
        float a  = yr[ca]      * sxr * sk[ci]      + bk[ci];
        float b2 = yr[ca + 64] * sxr * sk[ci + 64] + bk[ci + 64];
        float c  = cosb[s * HD_ + d], sn = sinb[s * HD_ + d];
        size_t base = (((size_t)(b * KV_ + kv)) * S_ + s) * HD_;
        Kb[base + d]      = f2bf(a * c - b2 * sn);
        Kb[base + d + 64] = f2bf(b2 * c + a * sn);
    }
    for (int p = t; p < KV_ * HD_; p += 256) {
        int kv = p >> 7, d = p & 127;
        int ci = kv * HD_ + d;
        int ca = H_ * HD_ + KV_ * HD_ + ci;
        float v = yr[ca] * sxr * sv[ci] + bv[ci];
        unsigned short vh = f2bf(v);
        float vrem = v - bf2f(vh);
        size_t idx = (((size_t)(b * KV_ + kv)) * HD_ + d) * S_ + s;
        Vh[idx] = vh;
        Vl[idx] = f2bf(vrem);
    }
}

// --------------------------- K5b: causal softmax, in-place fp32->bf16 -------
// Wave per row. P (bf16) overwrites the first half of the fp32 score row.
__global__ __launch_bounds__(256) void softmax_k(float* __restrict__ Sc)
{
    int z = blockIdx.y;
    int q = (blockIdx.x << 2) + (threadIdx.x >> 6);
    int lane = threadIdx.x & 63;
    float* sr = Sc + ((size_t)z * S_ + q) * S_;
    int nk = q + 1;
    int kbase = lane * 16;

    f32x4 v[4];
    #pragma unroll
    for (int i = 0; i < 4; i++) v[i] = *(const f32x4*)(sr + kbase + i*4);

    float m = -1e30f;
    #pragma unroll
    for (int i = 0; i < 4; i++)
        #pragma unroll
        for (int j = 0; j < 4; j++)
            if (kbase + i*4 + j < nk) m = fmaxf(m, v[i][j]);
    #pragma unroll
    for (int off = 32; off > 0; off >>= 1) m = fmaxf(m, __shfl_xor(m, off, 64));

    float sum = 0.f;
    #pragma unroll
    for (int i = 0; i < 4; i++)
        #pragma unroll
        for (int j = 0; j < 4; j++) {
            float e = (kbase + i*4 + j < nk) ? __expf(v[i][j] - m) : 0.f;
            v[i][j] = e;
            sum += e;
        }
    #pragma unroll
    for (int off = 32; off > 0; off >>= 1) sum += __shfl_xor(sum, off, 64);
    float inv = 1.0f / sum;

    unsigned short* pr = (unsigned short*)sr;   // row stride is 2048 shorts
    short8 o0, o1;
    #pragma unroll
    for (int j = 0; j < 8; j++) o0[j] = (short)f2bf(v[j >> 2][j & 3] * inv);
    #pragma unroll
    for (int j = 0; j < 8; j++) o1[j] = (short)f2bf(v[2 + (j >> 2)][j & 3] * inv);
    *(short8*)(pr + kbase)     = o0;
    *(short8*)(pr + kbase + 8) = o1;
}

// ---------------------------------------------------------------------------
extern "C" void kernel_launch(void* const* d_in, const int* in_sizes, int n_in,
                              void* d_out, int out_size, void* d_ws, size_t ws_size,
                              hipStream_t stream)
{
    (void)in_sizes; (void)n_in; (void)out_size;
    const float* x    = (const float*)d_in[0];
    const float* cosb = (const float*)d_in[1];
    const float* sinb = (const float*)d_in[2];
    const int*   wq   = (const int*)d_in[3];
    const float* sq   = (const float*)d_in[4];
    const float* bq   = (const float*)d_in[5];
    const int*   wk   = (const int*)d_in[6];
    const float* sk   = (const float*)d_in[7];
    const float* bk   = (const float*)d_in[8];
    const int*   wv   = (const int*)d_in[9];
    const float* sv   = (const float*)d_in[10];
    const float* bv   = (const float*)d_in[11];
    const int*   wo   = (const int*)d_in[12];
    const float* so   = (const float*)d_in[13];
    float* out = (float*)d_out;
    char*  ws  = (char*)d_ws;

    // ws regions. fixed = 146817024 B; Sc chunk = PC*4 MiB (>= 64 MiB for Xi+Y).
    const size_t fixedB = 146817024ull;
    int PC = 16;
    if      (ws_size >= fixedB + 268435456ull) PC = 64;
    else if (ws_size >= fixedB + 134217728ull) PC = 32;
    size_t ScB = (size_t)PC * S_ * S_ * 4;
    size_t R1sz = (ScB > 67108864ull) ? ScB : 67108864ull;

    size_t R1 = 0;
    size_t R2 = R1 + R1sz;            // Wqkv | Oi
    size_t R3 = R2 + 50331648ull;     // Wo
    size_t R4 = R3 + 33554432ull;     // Q bf16 (16.8 MB)
    size_t R5 = R4 + 16777216ull;     // K bf16 (4.2 MB)
    size_t R6 = R5 + 4194304ull;      // V^T hi+lo (8.4 MB)
    size_t R7 = R6 + 8388608ull;      // O fp32 (33.5 MB)
    size_t R8 = R7 + 33554432ull;     // sx, sxo

    unsigned short* Xi   = (unsigned short*)(ws + R1);
    float*          Y    = (float*)(ws + R1 + 16777216ull);
    float*          Sc   = (float*)(ws + R1);
    unsigned short* Wqkv = (unsigned short*)(ws + R2);
    unsigned short* Oi   = (unsigned short*)(ws + R2);
    unsigned short* Wo   = (unsigned short*)(ws + R3);
    unsigned short* Q    = (unsigned short*)(ws + R4);
    unsigned short* Kb   = (unsigned short*)(ws + R5);
    unsigned short* Vh   = (unsigned short*)(ws + R6);
    unsigned short* Vl   = (unsigned short*)(ws + R6 + 4194304ull);
    float*          O    = (float*)(ws + R7);
    float*          sx   = (float*)(ws + R8);
    float*          sxo  = (float*)(ws + R8 + 8192);

    // K1: quantize x rows
    quantize_rows_k<<<dim3(NR), dim3(256), 0, stream>>>(x, Xi, sx, D_);

    // K2: weights -> bf16.  n4 = elems/4; grid = n4/256 blocks (R2 bug: was /4 of this)
    convert_w_k<<<dim3(16384), dim3(256), 0, stream>>>(wq, Wqkv,            4096*1024);
    convert_w_k<<<dim3( 4096), dim3(256), 0, stream>>>(wk, Wqkv + 16777216, 1024*1024);
    convert_w_k<<<dim3( 4096), dim3(256), 0, stream>>>(wv, Wqkv + 20971520, 1024*1024);
    convert_w_k<<<dim3(16384), dim3(256), 0, stream>>>(wo, Wo,              4096*1024);

    // K3: Y = Xi * Wqkv^T   (2048 x 6144, K=4096)
    gemm_bt_k<0><<<dim3(48,16,1), dim3(256), 0, stream>>>(
        Xi, Wqkv, nullptr, Y, nullptr, nullptr, NR, NQKV, D_, D_, D_, NQKV, 0);

    // K4: dequant + rope + pack (Q pre-scaled by 1/sqrt(HD))
    derope_k<<<dim3(NR), dim3(256), 0, stream>>>(
        Y, sx, sq, bq, sk, bk, sv, bv, cosb, sinb, Q, Kb, Vh, Vl);

    // K5: attention in chunks of PC (b,h) pairs
    int nch = 64 / PC;
    for (int c = 0; c < nch; ++c) {
        int zb = c * PC;
        gemm_bt_k<1><<<dim3(8,8,PC), dim3(256), 0, stream>>>(
            Q, Kb, nullptr, Sc, nullptr, nullptr, S_, S_, HD_, HD_, HD_, S_, zb);
        softmax_k<<<dim3(S_/4, PC), dim3(256), 0, stream>>>(Sc);
        gemm_bt_k<2><<<dim3(1,8,PC), dim3(256), 0, stream>>>(
            (const unsigned short*)Sc, Vh, Vl, O, nullptr, nullptr,
            S_, HD_, S_, 2048, S_, H_*HD_, zb);
    }

    // K6: quantize attention output rows
    quantize_rows_k<<<dim3(NR), dim3(256), 0, stream>>>(O, Oi, sxo, H_*HD_);

    // K7: out = (Oi * Wo^T) * sxo[row] * so[col]
    gemm_bt_k<3><<<dim3(32,16,1), dim3(256), 0, stream>>>(
        Oi, Wo, nullptr, out, sxo, so, NR, D_, D_, D_, D_, D_, 0);
}

// Round 4
// 605.244 us; speedup vs baseline: 2.0931x; 1.3357x over previous
//
#include <hip/hip_runtime.h>

// ---------------------------------------------------------------------------
// GroupedQueryAttention: int8 dynamic-quant QKV proj + RoPE + causal GQA + O proj
// B=2 S=1024 D=4096 H=32 KV=8 HD=128 GROUP=4
//
// R4: projection GEMMs (K3 QKV, K7 O) moved to mfma_i32_16x16x64_i8 with int8
// operands (exact int32 accumulate; half staged bytes, half K-iters, ~2x MFMA
// rate). Activations/weights stored int8. Softmax causal-trimmed to
// klim=(q&~127)+128 (exactly the region PV reads). Attention path unchanged
// from R3 (bf16 QK^T w/ block skip, in-place bf16 P, dual-B PV w/ K-trim).
// ---------------------------------------------------------------------------

#define B_   2
#define S_   1024
#define D_   4096
#define H_   32
#define KV_  8
#define HD_  128
#define NR   (B_ * S_)            // 2048 rows
#define NQKV (H_*HD_ + 2*KV_*HD_) // 6144

typedef __attribute__((ext_vector_type(8))) short  short8;
typedef __attribute__((ext_vector_type(4))) float  f32x4;
typedef __attribute__((ext_vector_type(4))) int    int4v;

static __device__ __forceinline__ unsigned short f2bf(float f) {
    unsigned u = __builtin_bit_cast(unsigned, f);
    u += 0x7fffu + ((u >> 16) & 1u);     // round-to-nearest-even
    return (unsigned short)(u >> 16);
}
static __device__ __forceinline__ float bf2f(unsigned short h) {
    unsigned u = ((unsigned)h) << 16;
    return __builtin_bit_cast(float, u);
}

// async global->LDS, 16 B per lane. LDS dest = wave-uniform base + lane*16.
static __device__ __forceinline__ void async_cp16(const void* g, void* l) {
    __builtin_amdgcn_global_load_lds(
        (const __attribute__((address_space(1))) void*)g,
        (__attribute__((address_space(3))) void*)l, 16, 0, 0);
}

// --------------------------- K1/K6: row quantization (fp32 -> int8) ---------
__global__ __launch_bounds__(256) void quantize_rows_k(
    const float* __restrict__ X, signed char* __restrict__ Xq,
    float* __restrict__ sx_out, int K)
{
    int row = blockIdx.x;
    const float* xr = X + (size_t)row * K;
    int t = threadIdx.x;
    float m = 0.f;
    for (int j = t; j < K; j += 256) m = fmaxf(m, fabsf(xr[j]));
    for (int off = 32; off > 0; off >>= 1) m = fmaxf(m, __shfl_down(m, off, 64));
    __shared__ float red[4];
    if ((t & 63) == 0) red[t >> 6] = m;
    __syncthreads();
    float mm = fmaxf(fmaxf(red[0], red[1]), fmaxf(red[2], red[3]));
    float sx = mm / 127.0f;
    if (sx == 0.f) sx = 1.f;
    if (t == 0) sx_out[row] = sx;
    for (int j = t; j < K; j += 256) {
        float v = rintf(xr[j] / sx);
        v = fminf(fmaxf(v, -127.f), 127.f);
        Xq[(size_t)row * K + j] = (signed char)v;   // v is integral, exact
    }
}

// --------------------------- K2: weight convert (int32 -> int8) -------------
// 16 source ints -> 16 bytes per thread.
__global__ __launch_bounds__(256) void convert_w_i8(
    const int* __restrict__ W, signed char* __restrict__ Wb, int n16)
{
    int i = blockIdx.x * 256 + threadIdx.x;
    if (i >= n16) return;
    const int4v* src = (const int4v*)(W + (size_t)i * 16);
    int4v a = src[0], b = src[1], c = src[2], d = src[3];
    int4v o;
    o[0] = (a[0]&0xff) | ((a[1]&0xff)<<8) | ((a[2]&0xff)<<16) | ((a[3]&0xff)<<24);
    o[1] = (b[0]&0xff) | ((b[1]&0xff)<<8) | ((b[2]&0xff)<<16) | ((b[3]&0xff)<<24);
    o[2] = (c[0]&0xff) | ((c[1]&0xff)<<8) | ((c[2]&0xff)<<16) | ((c[3]&0xff)<<24);
    o[3] = (d[0]&0xff) | ((d[1]&0xff)<<8) | ((d[2]&0xff)<<16) | ((d[3]&0xff)<<24);
    *(int4v*)(Wb + (size_t)i * 16) = o;
}

// --------------------------- int8 GEMM: C = A * B^T (i8 -> i32 -> f32) ------
// A: M x K int8 row-major, Bm: N x K int8 row-major. 128x128 tile, BK=64.
// MODE 0: C = float(acc).   MODE 3: C = float(acc) * rs[row] * cs[col].
template<int MODE>
__global__ __launch_bounds__(256) void gemm_i8_k(
    const signed char* __restrict__ A, const signed char* __restrict__ Bm,
    float* __restrict__ C, const float* __restrict__ rs,
    const float* __restrict__ cs, int K, int lda, int ldb, int ldc)
{
    __shared__ __align__(16) signed char As[128 * 64];
    __shared__ __align__(16) signed char Bs[128 * 64];

    int t    = threadIdx.x;
    int m0   = blockIdx.y * 128;
    int n0   = blockIdx.x * 128;
    int lane = t & 63;
    int w    = t >> 6;
    int wm   = (w >> 1) * 64;
    int wn   = (w & 1) * 64;
    int l15  = lane & 15;
    int quad = lane >> 4;

    int4v acc[4][4];
    #pragma unroll
    for (int i = 0; i < 4; i++)
        #pragma unroll
        for (int j = 0; j < 4; j++) { int4v z = {0,0,0,0}; acc[i][j] = z; }

    int srow = t >> 2;            // 0..63
    int scol = (t & 3) * 16;      // 0,16,32,48 (bytes within 64-B row)
    signed char* lA0 = As + w * 1024;
    signed char* lA1 = As + 4096 + w * 1024;
    signed char* lB0 = Bs + w * 1024;
    signed char* lB1 = Bs + 4096 + w * 1024;

    for (int k0 = 0; k0 < K; k0 += 64) {
        const signed char* ga = A  + (size_t)(m0 + srow) * lda + k0 + scol;
        const signed char* gb = Bm + (size_t)(n0 + srow) * ldb + k0 + scol;
        async_cp16(ga, lA0);
        async_cp16(ga + (size_t)64 * lda, lA1);
        async_cp16(gb, lB0);
        async_cp16(gb + (size_t)64 * ldb, lB1);
        __syncthreads();

        int4v af[4], bf[4];
        #pragma unroll
        for (int i = 0; i < 4; i++) {
            af[i] = *(const int4v*)&As[(wm + i*16 + l15) * 64 + quad * 16];
            bf[i] = *(const int4v*)&Bs[(wn + i*16 + l15) * 64 + quad * 16];
        }
        #pragma unroll
        for (int i = 0; i < 4; i++)
            #pragma unroll
            for (int j = 0; j < 4; j++)
                acc[i][j] = __builtin_amdgcn_mfma_i32_16x16x64_i8(af[i], bf[j], acc[i][j], 0, 0, 0);
        __syncthreads();
    }

    #pragma unroll
    for (int i = 0; i < 4; i++) {
        #pragma unroll
        for (int j = 0; j < 4; j++) {
            #pragma unroll
            for (int r = 0; r < 4; r++) {
                int row = m0 + wm + i*16 + quad*4 + r;
                int col = n0 + wn + j*16 + l15;
                float v = (float)acc[i][j][r];
                if (MODE == 3) v *= rs[row] * cs[col];
                C[(size_t)row * ldc + col] = v;
            }
        }
    }
}

// --------------------------- bf16 GEMM: C = A * B^T (attention) -------------
// MODE 1: QK^T batch, causal block skip.
// MODE 2: PV batch, dual-B (Vh+Vl), causal K-trim, C strided into O.
#define BM 128
#define BN 128
#define BK 32

template<int MODE>
__global__ __launch_bounds__(256) void gemm_bt_k(
    const unsigned short* __restrict__ Aall,
    const unsigned short* __restrict__ Ball,
    const unsigned short* __restrict__ B2all,
    float* __restrict__ Call,
    int K, int lda, int ldb, int ldc, int zbase)
{
    if (MODE == 1 && blockIdx.x > blockIdx.y) return;   // fully-masked block

    const unsigned short* A  = Aall;
    const unsigned short* Bm = Ball;
    const unsigned short* B2 = B2all;
    float* C = Call;
    if (MODE == 1) {
        int zg = zbase + blockIdx.z;                 // global (b,h) pair
        A  += (size_t)zg * (S_ * HD_);               // Q
        Bm += (size_t)(zg >> 2) * (S_ * HD_);        // K kv-head
        C  += (size_t)blockIdx.z * (S_ * S_);        // Sc chunk-local
    } else if (MODE == 2) {
        int zg = zbase + blockIdx.z;
        A  += (size_t)blockIdx.z * ((size_t)S_ * 2048);  // P in-place rows (stride 2048)
        Bm += (size_t)(zg >> 2) * (HD_ * S_);        // V^T hi
        B2 += (size_t)(zg >> 2) * (HD_ * S_);        // V^T lo
        C  += (size_t)(zg >> 5) * ((size_t)S_ * (H_*HD_)) + (size_t)(zg & 31) * HD_;
    }

    __shared__ __align__(16) unsigned short As[BM * BK];
    __shared__ __align__(16) unsigned short Bs[BN * BK];
    __shared__ __align__(16) unsigned short Bs2[(MODE == 2) ? BN * BK : 8];

    int t    = threadIdx.x;
    int m0   = blockIdx.y * BM;
    int n0   = blockIdx.x * BN;
    int lane = t & 63;
    int w    = t >> 6;
    int wm   = (w >> 1) * 64;
    int wn   = (w & 1) * 64;
    int l15  = lane & 15;
    int quad = lane >> 4;

    f32x4 acc[4][4];
    #pragma unroll
    for (int i = 0; i < 4; i++)
        #pragma unroll
        for (int j = 0; j < 4; j++) { f32x4 z = {0.f,0.f,0.f,0.f}; acc[i][j] = z; }

    int srow = t >> 2;            // 0..63
    int scol = (t & 3) * 8;       // shorts
    unsigned short* lA0 = &As[w * 512];
    unsigned short* lA1 = &As[2048 + w * 512];
    unsigned short* lB0 = &Bs[w * 512];
    unsigned short* lB1 = &Bs[2048 + w * 512];
    unsigned short* lC0 = &Bs2[(MODE == 2) ? w * 512 : 0];
    unsigned short* lC1 = &Bs2[(MODE == 2) ? 2048 + w * 512 : 0];

    int kend = (MODE == 2) ? ((m0 + BM < K) ? m0 + BM : K) : K;   // causal trim

    for (int k0 = 0; k0 < kend; k0 += BK) {
        const unsigned short* ga = A  + (size_t)(m0 + srow) * lda + k0 + scol;
        const unsigned short* gb = Bm + (size_t)(n0 + srow) * ldb + k0 + scol;
        async_cp16(ga, lA0);
        async_cp16(ga + (size_t)64 * lda, lA1);
        async_cp16(gb, lB0);
        async_cp16(gb + (size_t)64 * ldb, lB1);
        if (MODE == 2) {
            const unsigned short* gb2 = B2 + (size_t)(n0 + srow) * ldb + k0 + scol;
            async_cp16(gb2, lC0);
            async_cp16(gb2 + (size_t)64 * ldb, lC1);
        }
        __syncthreads();

        short8 af[4], bf[4], bf2[4];
        #pragma unroll
        for (int i = 0; i < 4; i++) {
            af[i] = *(const short8*)&As[(wm + i*16 + l15) * BK + quad * 8];
            bf[i] = *(const short8*)&Bs[(wn + i*16 + l15) * BK + quad * 8];
            if (MODE == 2)
                bf2[i] = *(const short8*)&Bs2[(wn + i*16 + l15) * BK + quad * 8];
        }
        #pragma unroll
        for (int i = 0; i < 4; i++)
            #pragma unroll
            for (int j = 0; j < 4; j++) {
                acc[i][j] = __builtin_amdgcn_mfma_f32_16x16x32_bf16(af[i], bf[j], acc[i][j], 0, 0, 0);
                if (MODE == 2)
                    acc[i][j] = __builtin_amdgcn_mfma_f32_16x16x32_bf16(af[i], bf2[j], acc[i][j], 0, 0, 0);
            }
        __syncthreads();
    }

    #pragma unroll
    for (int i = 0; i < 4; i++) {
        #pragma unroll
        for (int j = 0; j < 4; j++) {
            #pragma unroll
            for (int r = 0; r < 4; r++) {
                int row = m0 + wm + i*16 + quad*4 + r;
                int col = n0 + wn + j*16 + l15;
                C[(size_t)row * ldc + col] = acc[i][j][r];
            }
        }
    }
}

// --------------------------- K4: dequant + bias + rope + pack ---------------
__global__ __launch_bounds__(256) void derope_k(
    const float* __restrict__ Y, const float* __restrict__ sx,
    const float* __restrict__ sq, const float* __restrict__ bq,
    const float* __restrict__ sk, const float* __restrict__ bk,
    const float* __restrict__ sv, const float* __restrict__ bv,
    const float* __restrict__ cosb, const float* __restrict__ sinb,
    unsigned short* __restrict__ Q, unsigned short* __restrict__ Kb,
    unsigned short* __restrict__ Vh, unsigned short* __restrict__ Vl)
{
    const float qs = 0.08838834764831845f;   // 1/sqrt(HD) folded into Q
    int r = blockIdx.x;               // (b,s)
    int b = r >> 10;
    int s = r & (S_ - 1);
    float sxr = sx[r];
    const float* yr = Y + (size_t)r * NQKV;
    int t = threadIdx.x;

    for (int p = t; p < H_ * 64; p += 256) {
        int h = p >> 6, d = p & 63;
        int ca = h * HD_ + d;
        float a  = yr[ca]      * sxr * sq[ca]      + bq[ca];
        float b2 = yr[ca + 64] * sxr * sq[ca + 64] + bq[ca + 64];
        float c  = cosb[s * HD_ + d], sn = sinb[s * HD_ + d];
        size_t base = (((size_t)(b * H_ + h)) * S_ + s) * HD_;
        Q[base + d]      = f2bf((a * c - b2 * sn) * qs);
        Q[base + d + 64] = f2bf((b2 * c + a * sn) * qs);
    }
    for (int p = t; p < KV_ * 64; p += 256) {
        int kv = p >> 6, d = p & 63;
        int ci = kv * HD_ + d;
        int ca = H_ * HD_ + ci;
        float a  = yr[ca]      * sxr * sk[ci]      + bk[ci];
        float b2 = yr[ca + 64] * sxr * sk[ci + 64] + bk[ci + 64];
        float c  = cosb[s * HD_ + d], sn = sinb[s * HD_ + d];
        size_t base = (((size_t)(b * KV_ + kv)) * S_ + s) * HD_;
        Kb[base + d]      = f2bf(a * c - b2 * sn);
        Kb[base + d + 64] = f2bf(b2 * c + a * sn);
    }
    for (int p = t; p < KV_ * HD_; p += 256) {
        int kv = p >> 7, d = p & 127;
        int ci = kv * HD_ + d;
        int ca = H_ * HD_ + KV_ * HD_ + ci;
        float v = yr[ca] * sxr * sv[ci] + bv[ci];
        unsigned short vh = f2bf(v);
        float vrem = v - bf2f(vh);
        size_t idx = (((size_t)(b * KV_ + kv)) * HD_ + d) * S_ + s;
        Vh[idx] = vh;
        Vl[idx] = f2bf(vrem);
    }
}

// --------------------------- K5b: causal softmax, in-place fp32->bf16 -------
// Wave per row; only cols < klim=(q&~127)+128 touched (exactly what PV reads).
__global__ __launch_bounds__(256) void softmax_k(float* __restrict__ Sc)
{
    int z = blockIdx.y;
    int q = (blockIdx.x << 2) + (threadIdx.x >> 6);
    int lane = threadIdx.x & 63;
    float* sr = Sc + ((size_t)z * S_ + q) * S_;
    int nk = q + 1;
    int klim = (q & ~127) + 128;
    int kbase = lane * 16;
    bool act = kbase < klim;

    f32x4 v[4];
    #pragma unroll
    for (int i = 0; i < 4; i++) {
        if (act) v[i] = *(const f32x4*)(sr + kbase + i*4);
        else     { f32x4 z4 = {0.f,0.f,0.f,0.f}; v[i] = z4; }
    }

    float m = -1e30f;
    #pragma unroll
    for (int i = 0; i < 4; i++)
        #pragma unroll
        for (int j = 0; j < 4; j++)
            if (kbase + i*4 + j < nk) m = fmaxf(m, v[i][j]);
    #pragma unroll
    for (int off = 32; off > 0; off >>= 1) m = fmaxf(m, __shfl_xor(m, off, 64));

    float sum = 0.f;
    #pragma unroll
    for (int i = 0; i < 4; i++)
        #pragma unroll
        for (int j = 0; j < 4; j++) {
            float e = (kbase + i*4 + j < nk) ? __expf(v[i][j] - m) : 0.f;
            v[i][j] = e;
            sum += e;
        }
    #pragma unroll
    for (int off = 32; off > 0; off >>= 1) sum += __shfl_xor(sum, off, 64);
    float inv = 1.0f / sum;

    if (act) {
        unsigned short* pr = (unsigned short*)sr;   // row stride 2048 shorts
        short8 o0, o1;
        #pragma unroll
        for (int j = 0; j < 8; j++) o0[j] = (short)f2bf(v[j >> 2][j & 3] * inv);
        #pragma unroll
        for (int j = 0; j < 8; j++) o1[j] = (short)f2bf(v[2 + (j >> 2)][j & 3] * inv);
        *(short8*)(pr + kbase)     = o0;
        *(short8*)(pr + kbase + 8) = o1;
    }
}

// ---------------------------------------------------------------------------
extern "C" void kernel_launch(void* const* d_in, const int* in_sizes, int n_in,
                              void* d_out, int out_size, void* d_ws, size_t ws_size,
                              hipStream_t stream)
{
    (void)in_sizes; (void)n_in; (void)out_size;
    const float* x    = (const float*)d_in[0];
    const float* cosb = (const float*)d_in[1];
    const float* sinb = (const float*)d_in[2];
    const int*   wq   = (const int*)d_in[3];
    const float* sq   = (const float*)d_in[4];
    const float* bq   = (const float*)d_in[5];
    const int*   wk   = (const int*)d_in[6];
    const float* sk   = (const float*)d_in[7];
    const float* bk   = (const float*)d_in[8];
    const int*   wv   = (const int*)d_in[9];
    const float* sv   = (const float*)d_in[10];
    const float* bv   = (const float*)d_in[11];
    const int*   wo   = (const int*)d_in[12];
    const float* so   = (const float*)d_in[13];
    float* out = (float*)d_out;
    char*  ws  = (char*)d_ws;

    // ws regions. fixed = 104,873,984 B; Sc chunk = PC*4 MiB (>= Xi+Y = 58.7 MB).
    const size_t fixedB = 104873984ull;
    int PC = 16;
    if      (ws_size >= fixedB + 268435456ull) PC = 64;
    else if (ws_size >= fixedB + 134217728ull) PC = 32;
    size_t ScB = (size_t)PC * S_ * S_ * 4;
    size_t R1sz = (ScB > 67108864ull) ? ScB : 67108864ull;

    size_t R1 = 0;
    size_t R2 = R1 + R1sz;            // Wqkv i8 (25.2 MB) | Oi i8 (8.4 MB)
    size_t R3 = R2 + 25165824ull;     // Wo i8 (16.8 MB)
    size_t R4 = R3 + 16777216ull;     // Q bf16 (16.8 MB)
    size_t R5 = R4 + 16777216ull;     // K bf16 (4.2 MB)
    size_t R6 = R5 + 4194304ull;      // V^T hi+lo (8.4 MB)
    size_t R7 = R6 + 8388608ull;      // O fp32 (33.5 MB)
    size_t R8 = R7 + 33554432ull;     // sx, sxo

    signed char*    Xi   = (signed char*)(ws + R1);
    float*          Y    = (float*)(ws + R1 + 8388608ull);
    float*          Sc   = (float*)(ws + R1);
    signed char*    Wqkv = (signed char*)(ws + R2);
    signed char*    Oi   = (signed char*)(ws + R2);
    signed char*    Wo   = (signed char*)(ws + R3);
    unsigned short* Q    = (unsigned short*)(ws + R4);
    unsigned short* Kb   = (unsigned short*)(ws + R5);
    unsigned short* Vh   = (unsigned short*)(ws + R6);
    unsigned short* Vl   = (unsigned short*)(ws + R6 + 4194304ull);
    float*          O    = (float*)(ws + R7);
    float*          sx   = (float*)(ws + R8);
    float*          sxo  = (float*)(ws + R8 + 8192);

    // K1: quantize x rows -> int8
    quantize_rows_k<<<dim3(NR), dim3(256), 0, stream>>>(x, Xi, sx, D_);

    // K2: weights -> int8 (16 elems/thread)
    convert_w_i8<<<dim3(4096), dim3(256), 0, stream>>>(wq, Wqkv,            4096*256);
    convert_w_i8<<<dim3(1024), dim3(256), 0, stream>>>(wk, Wqkv + 16777216, 1024*256);
    convert_w_i8<<<dim3(1024), dim3(256), 0, stream>>>(wv, Wqkv + 20971520, 1024*256);
    convert_w_i8<<<dim3(4096), dim3(256), 0, stream>>>(wo, Wo,              4096*256);

    // K3: Y = Xi * Wqkv^T   (2048 x 6144, K=4096, int8 MFMA)
    gemm_i8_k<0><<<dim3(48,16,1), dim3(256), 0, stream>>>(
        Xi, Wqkv, Y, nullptr, nullptr, D_, D_, D_, NQKV);

    // K4: dequant + rope + pack (Q pre-scaled by 1/sqrt(HD))
    derope_k<<<dim3(NR), dim3(256), 0, stream>>>(
        Y, sx, sq, bq, sk, bk, sv, bv, cosb, sinb, Q, Kb, Vh, Vl);

    // K5: attention in chunks of PC (b,h) pairs
    int nch = 64 / PC;
    for (int c = 0; c < nch; ++c) {
        int zb = c * PC;
        gemm_bt_k<1><<<dim3(8,8,PC), dim3(256), 0, stream>>>(
            Q, Kb, nullptr, Sc, HD_, HD_, HD_, S_, zb);
        softmax_k<<<dim3(S_/4, PC), dim3(256), 0, stream>>>(Sc);
        gemm_bt_k<2><<<dim3(1,8,PC), dim3(256), 0, stream>>>(
            (const unsigned short*)Sc, Vh, Vl, O, S_, 2048, S_, H_*HD_, zb);
    }

    // K6: quantize attention output rows -> int8
    quantize_rows_k<<<dim3(NR), dim3(256), 0, stream>>>(O, Oi, sxo, H_*HD_);

    // K7: out = float(Oi * Wo^T) * sxo[row] * so[col]  (int8 MFMA)
    gemm_i8_k<3><<<dim3(32,16,1), dim3(256), 0, stream>>>(
        Oi, Wo, out, sxo, so, D_, D_, D_, D_);
}

// Round 5
// 488.029 us; speedup vs baseline: 2.5958x; 1.2402x over previous
//
#include <hip/hip_runtime.h>

// ---------------------------------------------------------------------------
// GroupedQueryAttention: int8 dynamic-quant QKV proj + RoPE + causal GQA + O proj
// B=2 S=1024 D=4096 H=32 KV=8 HD=128 GROUP=4
//
// R5: attention fused into one flash-style kernel (online softmax, P round-
// trip through LDS per the verified C-layout->A-frag transform). Sc/P buffers
// and their ~430 MB of HBM traffic removed; V lo-order term dropped.
// Projections stay on mfma_i32_16x16x64_i8 (exact int32 accumulate).
// ---------------------------------------------------------------------------

#define B_   2
#define S_   1024
#define D_   4096
#define H_   32
#define KV_  8
#define HD_  128
#define NR   (B_ * S_)            // 2048 rows
#define NQKV (H_*HD_ + 2*KV_*HD_) // 6144

typedef __attribute__((ext_vector_type(8))) short  short8;
typedef __attribute__((ext_vector_type(4))) float  f32x4;
typedef __attribute__((ext_vector_type(4))) int    int4v;

static __device__ __forceinline__ unsigned short f2bf(float f) {
    unsigned u = __builtin_bit_cast(unsigned, f);
    u += 0x7fffu + ((u >> 16) & 1u);     // round-to-nearest-even
    return (unsigned short)(u >> 16);
}

// async global->LDS, 16 B per lane. LDS dest = wave-uniform base + lane*16.
static __device__ __forceinline__ void async_cp16(const void* g, void* l) {
    __builtin_amdgcn_global_load_lds(
        (const __attribute__((address_space(1))) void*)g,
        (__attribute__((address_space(3))) void*)l, 16, 0, 0);
}

// --------------------------- K1/K6: row quantization (fp32 -> int8) ---------
__global__ __launch_bounds__(256) void quantize_rows_k(
    const float* __restrict__ X, signed char* __restrict__ Xq,
    float* __restrict__ sx_out, int K)
{
    int row = blockIdx.x;
    const float* xr = X + (size_t)row * K;
    int t = threadIdx.x;
    float m = 0.f;
    for (int j = t; j < K; j += 256) m = fmaxf(m, fabsf(xr[j]));
    for (int off = 32; off > 0; off >>= 1) m = fmaxf(m, __shfl_down(m, off, 64));
    __shared__ float red[4];
    if ((t & 63) == 0) red[t >> 6] = m;
    __syncthreads();
    float mm = fmaxf(fmaxf(red[0], red[1]), fmaxf(red[2], red[3]));
    float sx = mm / 127.0f;
    if (sx == 0.f) sx = 1.f;
    if (t == 0) sx_out[row] = sx;
    for (int j = t; j < K; j += 256) {
        float v = rintf(xr[j] / sx);
        v = fminf(fmaxf(v, -127.f), 127.f);
        Xq[(size_t)row * K + j] = (signed char)v;   // v is integral, exact
    }
}

// --------------------------- K2: weight convert (int32 -> int8) -------------
__global__ __launch_bounds__(256) void convert_w_i8(
    const int* __restrict__ W, signed char* __restrict__ Wb, int n16)
{
    int i = blockIdx.x * 256 + threadIdx.x;
    if (i >= n16) return;
    const int4v* src = (const int4v*)(W + (size_t)i * 16);
    int4v a = src[0], b = src[1], c = src[2], d = src[3];
    int4v o;
    o[0] = (a[0]&0xff) | ((a[1]&0xff)<<8) | ((a[2]&0xff)<<16) | ((a[3]&0xff)<<24);
    o[1] = (b[0]&0xff) | ((b[1]&0xff)<<8) | ((b[2]&0xff)<<16) | ((b[3]&0xff)<<24);
    o[2] = (c[0]&0xff) | ((c[1]&0xff)<<8) | ((c[2]&0xff)<<16) | ((c[3]&0xff)<<24);
    o[3] = (d[0]&0xff) | ((d[1]&0xff)<<8) | ((d[2]&0xff)<<16) | ((d[3]&0xff)<<24);
    *(int4v*)(Wb + (size_t)i * 16) = o;
}

// --------------------------- int8 GEMM: C = A * B^T (i8 -> i32 -> f32) ------
// MODE 0: C = float(acc).   MODE 3: C = float(acc) * rs[row] * cs[col].
template<int MODE>
__global__ __launch_bounds__(256) void gemm_i8_k(
    const signed char* __restrict__ A, const signed char* __restrict__ Bm,
    float* __restrict__ C, const float* __restrict__ rs,
    const float* __restrict__ cs, int K, int lda, int ldb, int ldc)
{
    __shared__ __align__(16) signed char As[128 * 64];
    __shared__ __align__(16) signed char Bs[128 * 64];

    int t    = threadIdx.x;
    int m0   = blockIdx.y * 128;
    int n0   = blockIdx.x * 128;
    int lane = t & 63;
    int w    = t >> 6;
    int wm   = (w >> 1) * 64;
    int wn   = (w & 1) * 64;
    int l15  = lane & 15;
    int quad = lane >> 4;

    int4v acc[4][4];
    #pragma unroll
    for (int i = 0; i < 4; i++)
        #pragma unroll
        for (int j = 0; j < 4; j++) { int4v z = {0,0,0,0}; acc[i][j] = z; }

    int srow = t >> 2;            // 0..63
    int scol = (t & 3) * 16;      // bytes within 64-B row
    signed char* lA0 = As + w * 1024;
    signed char* lA1 = As + 4096 + w * 1024;
    signed char* lB0 = Bs + w * 1024;
    signed char* lB1 = Bs + 4096 + w * 1024;

    for (int k0 = 0; k0 < K; k0 += 64) {
        const signed char* ga = A  + (size_t)(m0 + srow) * lda + k0 + scol;
        const signed char* gb = Bm + (size_t)(n0 + srow) * ldb + k0 + scol;
        async_cp16(ga, lA0);
        async_cp16(ga + (size_t)64 * lda, lA1);
        async_cp16(gb, lB0);
        async_cp16(gb + (size_t)64 * ldb, lB1);
        __syncthreads();

        int4v af[4], bf[4];
        #pragma unroll
        for (int i = 0; i < 4; i++) {
            af[i] = *(const int4v*)&As[(wm + i*16 + l15) * 64 + quad * 16];
            bf[i] = *(const int4v*)&Bs[(wn + i*16 + l15) * 64 + quad * 16];
        }
        #pragma unroll
        for (int i = 0; i < 4; i++)
            #pragma unroll
            for (int j = 0; j < 4; j++)
                acc[i][j] = __builtin_amdgcn_mfma_i32_16x16x64_i8(af[i], bf[j], acc[i][j], 0, 0, 0);
        __syncthreads();
    }

    #pragma unroll
    for (int i = 0; i < 4; i++) {
        #pragma unroll
        for (int j = 0; j < 4; j++) {
            #pragma unroll
            for (int r = 0; r < 4; r++) {
                int row = m0 + wm + i*16 + quad*4 + r;
                int col = n0 + wn + j*16 + l15;
                float v = (float)acc[i][j][r];
                if (MODE == 3) v *= rs[row] * cs[col];
                C[(size_t)row * ldc + col] = v;
            }
        }
    }
}

// --------------------------- K4: dequant + bias + rope + pack ---------------
__global__ __launch_bounds__(256) void derope_k(
    const float* __restrict__ Y, const float* __restrict__ sx,
    const float* __restrict__ sq, const float* __restrict__ bq,
    const float* __restrict__ sk, const float* __restrict__ bk,
    const float* __restrict__ sv, const float* __restrict__ bv,
    const float* __restrict__ cosb, const float* __restrict__ sinb,
    unsigned short* __restrict__ Q, unsigned short* __restrict__ Kb,
    unsigned short* __restrict__ Vt)
{
    const float qs = 0.08838834764831845f;   // 1/sqrt(HD) folded into Q
    int r = blockIdx.x;               // (b,s)
    int b = r >> 10;
    int s = r & (S_ - 1);
    float sxr = sx[r];
    const float* yr = Y + (size_t)r * NQKV;
    int t = threadIdx.x;

    for (int p = t; p < H_ * 64; p += 256) {
        int h = p >> 6, d = p & 63;
        int ca = h * HD_ + d;
        float a  = yr[ca]      * sxr * sq[ca]      + bq[ca];
        float b2 = yr[ca + 64] * sxr * sq[ca + 64] + bq[ca + 64];
        float c  = cosb[s * HD_ + d], sn = sinb[s * HD_ + d];
        size_t base = (((size_t)(b * H_ + h)) * S_ + s) * HD_;
        Q[base + d]      = f2bf((a * c - b2 * sn) * qs);
        Q[base + d + 64] = f2bf((b2 * c + a * sn) * qs);
    }
    for (int p = t; p < KV_ * 64; p += 256) {
        int kv = p >> 6, d = p & 63;
        int ci = kv * HD_ + d;
        int ca = H_ * HD_ + ci;
        float a  = yr[ca]      * sxr * sk[ci]      + bk[ci];
        float b2 = yr[ca + 64] * sxr * sk[ci + 64] + bk[ci + 64];
        float c  = cosb[s * HD_ + d], sn = sinb[s * HD_ + d];
        size_t base = (((size_t)(b * KV_ + kv)) * S_ + s) * HD_;
        Kb[base + d]      = f2bf(a * c - b2 * sn);
        Kb[base + d + 64] = f2bf(b2 * c + a * sn);
    }
    for (int p = t; p < KV_ * HD_; p += 256) {
        int kv = p >> 7, d = p & 127;
        int ci = kv * HD_ + d;
        int ca = H_ * HD_ + KV_ * HD_ + ci;
        float v = yr[ca] * sxr * sv[ci] + bv[ci];
        size_t idx = (((size_t)(b * KV_ + kv)) * HD_ + d) * S_ + s;
        Vt[idx] = f2bf(v);               // V^T (b,kv,hd,s)
    }
}

// --------------------------- K5: fused flash attention ----------------------
// One block per (b*H+h, q-tile of 128). 4 waves; wave w owns q rows w*32..+31.
// Per K-tile j<=qt: stage K(128x128, contiguous) + V^T(128x128, row-strided)
// -> QK^T MFMA (S in C-layout regs) -> causal mask (diag tile) -> online
// softmax -> P(bf16) into LDS (reuses K buffer; wave-private q band) ->
// PV MFMA accumulate into fp32 O regs. Epilogue: O/l -> global fp32.
__global__ __launch_bounds__(256) void flash_attn_k(
    const unsigned short* __restrict__ Qg,   // (B,H,S,HD) bf16, *1/sqrt(HD)
    const unsigned short* __restrict__ Kg,   // (B,KV,S,HD) bf16
    const unsigned short* __restrict__ Vg,   // (B,KV,HD,S) bf16
    float* __restrict__ O)                   // (B*S, H*HD) fp32
{
    __shared__ __align__(16) unsigned short Ks[128 * HD_];   // 32 KB; becomes Ps
    __shared__ __align__(16) unsigned short Vs[HD_ * 128];   // 32 KB

    int pair = blockIdx.x;              // b*H + h
    int qt   = 7 - blockIdx.y;          // big q-tiles dispatched first
    int b    = pair >> 5;
    int kv   = (pair & 31) >> 2;

    const unsigned short* Qb = Qg + ((size_t)pair * S_ + qt * 128) * HD_;
    const unsigned short* Kb = Kg + ((size_t)(b * KV_ + kv)) * (S_ * HD_);
    const unsigned short* Vb = Vg + ((size_t)(b * KV_ + kv)) * (HD_ * S_);

    int t    = threadIdx.x;
    int lane = t & 63;
    int w    = t >> 6;
    int l15  = lane & 15;
    int quad = lane >> 4;

    // Q A-frags, loaded once: rows w*32 + i*16 + l15, k = ks*32 + quad*8 + j
    short8 qf[2][4];
    #pragma unroll
    for (int i = 0; i < 2; i++)
        #pragma unroll
        for (int ks = 0; ks < 4; ks++)
            qf[i][ks] = *(const short8*)(Qb + (size_t)(w*32 + i*16 + l15) * HD_ + ks*32 + quad*8);

    f32x4 oacc[2][8];
    #pragma unroll
    for (int i = 0; i < 2; i++)
        #pragma unroll
        for (int n = 0; n < 8; n++) { f32x4 z = {0.f,0.f,0.f,0.f}; oacc[i][n] = z; }
    float mrow[2][4], lrow[2][4];
    #pragma unroll
    for (int i = 0; i < 2; i++)
        #pragma unroll
        for (int r = 0; r < 4; r++) { mrow[i][r] = -1e30f; lrow[i][r] = 0.f; }

    for (int j = 0; j <= qt; ++j) {
        int k0 = j * 128;
        // ---- stage K tile (contiguous 32 KB) and V^T tile (rows strided S_)
        {
            const unsigned short* ksrc = Kb + (size_t)k0 * HD_ + t * 8;
            char* kdst = (char*)Ks + w * 1024;
            #pragma unroll
            for (int it = 0; it < 8; ++it)
                async_cp16(ksrc + it * 2048, kdst + it * 4096);
            const unsigned short* vsrc = Vb + (size_t)(w*4 + quad) * S_ + k0 + l15 * 8;
            char* vdst = (char*)Vs + w * 1024;
            #pragma unroll
            for (int it = 0; it < 8; ++it)
                async_cp16(vsrc + (size_t)it * 16 * S_, vdst + it * 4096);
        }
        __syncthreads();

        // ---- S = Q * K^T  (C-layout: col=l15, row=quad*4+r; per wave 32qx128k)
        f32x4 sacc[2][8];
        #pragma unroll
        for (int i = 0; i < 2; i++)
            #pragma unroll
            for (int n = 0; n < 8; n++) { f32x4 z = {0.f,0.f,0.f,0.f}; sacc[i][n] = z; }
        #pragma unroll
        for (int n = 0; n < 8; n++) {
            short8 kf[4];
            #pragma unroll
            for (int ks = 0; ks < 4; ks++)
                kf[ks] = *(const short8*)&Ks[(n*16 + l15) * HD_ + ks*32 + quad*8];
            #pragma unroll
            for (int i = 0; i < 2; i++)
                #pragma unroll
                for (int ks = 0; ks < 4; ks++)
                    sacc[i][n] = __builtin_amdgcn_mfma_f32_16x16x32_bf16(qf[i][ks], kf[ks], sacc[i][n], 0, 0, 0);
        }

        // ---- causal mask on the diagonal tile
        if (j == qt) {
            #pragma unroll
            for (int i = 0; i < 2; i++)
                #pragma unroll
                for (int n = 0; n < 8; n++)
                    #pragma unroll
                    for (int r = 0; r < 4; r++) {
                        int qrow = w*32 + i*16 + quad*4 + r;
                        int kcol = n*16 + l15;
                        if (kcol > qrow) sacc[i][n][r] = -1e30f;
                    }
        }

        // ---- online softmax update (row = quad*4+r; reduce over 16-lane col group)
        #pragma unroll
        for (int i = 0; i < 2; i++)
            #pragma unroll
            for (int r = 0; r < 4; r++) {
                float mx = sacc[i][0][r];
                #pragma unroll
                for (int n = 1; n < 8; n++) mx = fmaxf(mx, sacc[i][n][r]);
                mx = fmaxf(mx, __shfl_xor(mx, 1, 64));
                mx = fmaxf(mx, __shfl_xor(mx, 2, 64));
                mx = fmaxf(mx, __shfl_xor(mx, 4, 64));
                mx = fmaxf(mx, __shfl_xor(mx, 8, 64));
                float mnew = fmaxf(mrow[i][r], mx);
                float alpha = __expf(mrow[i][r] - mnew);
                mrow[i][r] = mnew;
                float s = 0.f;
                #pragma unroll
                for (int n = 0; n < 8; n++) {
                    float e = __expf(sacc[i][n][r] - mnew);
                    sacc[i][n][r] = e;
                    s += e;
                }
                s += __shfl_xor(s, 1, 64);
                s += __shfl_xor(s, 2, 64);
                s += __shfl_xor(s, 4, 64);
                s += __shfl_xor(s, 8, 64);
                lrow[i][r] = lrow[i][r] * alpha + s;
                #pragma unroll
                for (int n = 0; n < 8; n++) oacc[i][n][r] *= alpha;
            }

        __syncthreads();   // all waves done reading Ks before P overwrites it

        // ---- P (bf16) -> LDS, C-layout scatter into wave-private q band
        unsigned short* Ps = Ks;
        #pragma unroll
        for (int i = 0; i < 2; i++)
            #pragma unroll
            for (int n = 0; n < 8; n++)
                #pragma unroll
                for (int r = 0; r < 4; r++)
                    Ps[(size_t)(w*32 + i*16 + quad*4 + r) * 128 + n*16 + l15] =
                        f2bf(sacc[i][n][r]);

        // ---- O += P * V   (A-frags from own band; no barrier needed)
        short8 pf[2][4];
        #pragma unroll
        for (int i = 0; i < 2; i++)
            #pragma unroll
            for (int ks = 0; ks < 4; ks++)
                pf[i][ks] = *(const short8*)&Ps[(w*32 + i*16 + l15) * 128 + ks*32 + quad*8];
        #pragma unroll
        for (int n = 0; n < 8; n++) {
            short8 vf[4];
            #pragma unroll
            for (int ks = 0; ks < 4; ks++)
                vf[ks] = *(const short8*)&Vs[(n*16 + l15) * 128 + ks*32 + quad*8];
            #pragma unroll
            for (int i = 0; i < 2; i++)
                #pragma unroll
                for (int ks = 0; ks < 4; ks++)
                    oacc[i][n] = __builtin_amdgcn_mfma_f32_16x16x32_bf16(pf[i][ks], vf[ks], oacc[i][n], 0, 0, 0);
        }
        __syncthreads();   // done with Ps/Vs before next staging
    }

    // ---- epilogue: normalize and store
    float* Ob = O + ((size_t)(b * S_ + qt * 128)) * (H_*HD_) + (pair & 31) * HD_;
    #pragma unroll
    for (int i = 0; i < 2; i++)
        #pragma unroll
        for (int r = 0; r < 4; r++) {
            float inv = 1.0f / lrow[i][r];
            int row = w*32 + i*16 + quad*4 + r;
            #pragma unroll
            for (int n = 0; n < 8; n++)
                Ob[(size_t)row * (H_*HD_) + n*16 + l15] = oacc[i][n][r] * inv;
        }
}

// ---------------------------------------------------------------------------
extern "C" void kernel_launch(void* const* d_in, const int* in_sizes, int n_in,
                              void* d_out, int out_size, void* d_ws, size_t ws_size,
                              hipStream_t stream)
{
    (void)in_sizes; (void)n_in; (void)out_size; (void)ws_size;
    const float* x    = (const float*)d_in[0];
    const float* cosb = (const float*)d_in[1];
    const float* sinb = (const float*)d_in[2];
    const int*   wq   = (const int*)d_in[3];
    const float* sq   = (const float*)d_in[4];
    const float* bq   = (const float*)d_in[5];
    const int*   wk   = (const int*)d_in[6];
    const float* sk   = (const float*)d_in[7];
    const float* bk   = (const float*)d_in[8];
    const int*   wv   = (const int*)d_in[9];
    const float* sv   = (const float*)d_in[10];
    const float* bv   = (const float*)d_in[11];
    const int*   wo   = (const int*)d_in[12];
    const float* so   = (const float*)d_in[13];
    float* out = (float*)d_out;
    char*  ws  = (char*)d_ws;

    // ws layout (~159.4 MB total)
    signed char*    Xi   = (signed char*)(ws + 0);              //  8.4 MB
    float*          Y    = (float*)(ws + 8388608ull);           // 50.3 MB
    signed char*    Wqkv = (signed char*)(ws + 58720256ull);    // 25.2 MB (Oi reuses)
    signed char*    Oi   = (signed char*)(ws + 58720256ull);
    signed char*    Wo   = (signed char*)(ws + 83886080ull);    // 16.8 MB
    unsigned short* Q    = (unsigned short*)(ws + 100663296ull);// 16.8 MB
    unsigned short* Kb   = (unsigned short*)(ws + 117440512ull);//  4.2 MB
    unsigned short* Vt   = (unsigned short*)(ws + 121634816ull);//  4.2 MB
    float*          O    = (float*)(ws + 125829120ull);         // 33.5 MB
    float*          sx   = (float*)(ws + 159383552ull);
    float*          sxo  = (float*)(ws + 159391744ull);

    // K1: quantize x rows -> int8
    quantize_rows_k<<<dim3(NR), dim3(256), 0, stream>>>(x, Xi, sx, D_);

    // K2: weights -> int8 (16 elems/thread)
    convert_w_i8<<<dim3(4096), dim3(256), 0, stream>>>(wq, Wqkv,            4096*256);
    convert_w_i8<<<dim3(1024), dim3(256), 0, stream>>>(wk, Wqkv + 16777216, 1024*256);
    convert_w_i8<<<dim3(1024), dim3(256), 0, stream>>>(wv, Wqkv + 20971520, 1024*256);
    convert_w_i8<<<dim3(4096), dim3(256), 0, stream>>>(wo, Wo,              4096*256);

    // K3: Y = Xi * Wqkv^T   (2048 x 6144, K=4096, int8 MFMA)
    gemm_i8_k<0><<<dim3(48,16,1), dim3(256), 0, stream>>>(
        Xi, Wqkv, Y, nullptr, nullptr, D_, D_, D_, NQKV);

    // K4: dequant + rope + pack (Q pre-scaled by 1/sqrt(HD))
    derope_k<<<dim3(NR), dim3(256), 0, stream>>>(
        Y, sx, sq, bq, sk, bk, sv, bv, cosb, sinb, Q, Kb, Vt);

    // K5: fused flash attention  (64 pairs x 8 q-tiles)
    flash_attn_k<<<dim3(64, 8), dim3(256), 0, stream>>>(Q, Kb, Vt, O);

    // K6: quantize attention output rows -> int8
    quantize_rows_k<<<dim3(NR), dim3(256), 0, stream>>>(O, Oi, sxo, H_*HD_);

    // K7: out = float(Oi * Wo^T) * sxo[row] * so[col]  (int8 MFMA)
    gemm_i8_k<3><<<dim3(32,16,1), dim3(256), 0, stream>>>(
        Oi, Wo, out, sxo, so, D_, D_, D_, D_);
}

// Round 6
// 442.737 us; speedup vs baseline: 2.8613x; 1.1023x over previous
//
#include <hip/hip_runtime.h>

// ---------------------------------------------------------------------------
// GroupedQueryAttention: int8 dynamic-quant QKV proj + RoPE + causal GQA + O proj
// B=2 S=1024 D=4096 H=32 KV=8 HD=128 GROUP=4
//
// R6: flash v2 — Q-tile 64 / K-tile 64, ds_write staging into PADDED LDS
// tiles (row stride ≡ 2 mod 32 banks: kills the 16-way frag-read conflicts),
// 34.3 KB LDS -> 4 blocks/CU, VGPR ~110 -> 4 waves/SIMD. convert_w fused to
// one launch; quantize_rows vectorized (float4 in, int8x4 out).
// Projections stay on mfma_i32_16x16x64_i8.
// ---------------------------------------------------------------------------

#define B_   2
#define S_   1024
#define D_   4096
#define H_   32
#define KV_  8
#define HD_  128
#define NR   (B_ * S_)            // 2048 rows
#define NQKV (H_*HD_ + 2*KV_*HD_) // 6144

#define KSTR 132                  // K/P tile row stride (shorts), 66 dw ≡ 2 mod 32
#define VSTR 68                   // V tile row stride (shorts), 34 dw ≡ 2 mod 32

typedef __attribute__((ext_vector_type(8))) short  short8;
typedef __attribute__((ext_vector_type(4))) float  f32x4;
typedef __attribute__((ext_vector_type(4))) int    int4v;

static __device__ __forceinline__ unsigned short f2bf(float f) {
    unsigned u = __builtin_bit_cast(unsigned, f);
    u += 0x7fffu + ((u >> 16) & 1u);     // round-to-nearest-even
    return (unsigned short)(u >> 16);
}

// async global->LDS, 16 B per lane. LDS dest = wave-uniform base + lane*16.
static __device__ __forceinline__ void async_cp16(const void* g, void* l) {
    __builtin_amdgcn_global_load_lds(
        (const __attribute__((address_space(1))) void*)g,
        (__attribute__((address_space(3))) void*)l, 16, 0, 0);
}

// --------------------------- K1/K6: row quantization (fp32 -> int8) ---------
// K fixed at 4096. float4 loads, values kept in regs, int8x4 packed stores.
__global__ __launch_bounds__(256) void quantize_rows_k(
    const float* __restrict__ X, signed char* __restrict__ Xq,
    float* __restrict__ sx_out)
{
    int row = blockIdx.x;
    const f32x4* xr = (const f32x4*)(X + (size_t)row * 4096);
    int t = threadIdx.x;

    f32x4 v[4];
    #pragma unroll
    for (int i = 0; i < 4; i++) v[i] = xr[t + i * 256];

    float m = 0.f;
    #pragma unroll
    for (int i = 0; i < 4; i++)
        #pragma unroll
        for (int j = 0; j < 4; j++) m = fmaxf(m, fabsf(v[i][j]));
    #pragma unroll
    for (int off = 32; off > 0; off >>= 1) m = fmaxf(m, __shfl_down(m, off, 64));
    __shared__ float red[4];
    if ((t & 63) == 0) red[t >> 6] = m;
    __syncthreads();
    float mm = fmaxf(fmaxf(red[0], red[1]), fmaxf(red[2], red[3]));
    float sx = mm / 127.0f;
    if (sx == 0.f) sx = 1.f;
    if (t == 0) sx_out[row] = sx;

    int* dst = (int*)(Xq + (size_t)row * 4096);
    #pragma unroll
    for (int i = 0; i < 4; i++) {
        int o = 0;
        #pragma unroll
        for (int j = 0; j < 4; j++) {
            float q = rintf(v[i][j] / sx);
            q = fminf(fmaxf(q, -127.f), 127.f);
            o |= (((int)q) & 0xff) << (j * 8);
        }
        dst[t + i * 256] = o;
    }
}

// --------------------------- K2: all weights -> int8, one launch ------------
// 16 source ints -> 16 bytes per thread. wq:1048576 | wk:262144 | wv:262144 | wo:1048576 (n16 units)
__global__ __launch_bounds__(256) void convert_all_w(
    const int* __restrict__ wq, const int* __restrict__ wk,
    const int* __restrict__ wv, const int* __restrict__ wo,
    signed char* __restrict__ Wqkv, signed char* __restrict__ Wo)
{
    int i = blockIdx.x * 256 + threadIdx.x;
    const int* src;
    signed char* dst;
    if (i < 1048576)      { src = wq + (size_t)i * 16;              dst = Wqkv + (size_t)i * 16; }
    else if (i < 1310720) { int j = i - 1048576; src = wk + (size_t)j * 16; dst = Wqkv + 16777216 + (size_t)j * 16; }
    else if (i < 1572864) { int j = i - 1310720; src = wv + (size_t)j * 16; dst = Wqkv + 20971520 + (size_t)j * 16; }
    else                  { int j = i - 1572864; src = wo + (size_t)j * 16; dst = Wo + (size_t)j * 16; }
    const int4v* s4 = (const int4v*)src;
    int4v a = s4[0], b = s4[1], c = s4[2], d = s4[3];
    int4v o;
    o[0] = (a[0]&0xff) | ((a[1]&0xff)<<8) | ((a[2]&0xff)<<16) | ((a[3]&0xff)<<24);
    o[1] = (b[0]&0xff) | ((b[1]&0xff)<<8) | ((b[2]&0xff)<<16) | ((b[3]&0xff)<<24);
    o[2] = (c[0]&0xff) | ((c[1]&0xff)<<8) | ((c[2]&0xff)<<16) | ((c[3]&0xff)<<24);
    o[3] = (d[0]&0xff) | ((d[1]&0xff)<<8) | ((d[2]&0xff)<<16) | ((d[3]&0xff)<<24);
    *(int4v*)dst = o;
}

// --------------------------- int8 GEMM: C = A * B^T (i8 -> i32 -> f32) ------
// MODE 0: C = float(acc).   MODE 3: C = float(acc) * rs[row] * cs[col].
template<int MODE>
__global__ __launch_bounds__(256) void gemm_i8_k(
    const signed char* __restrict__ A, const signed char* __restrict__ Bm,
    float* __restrict__ C, const float* __restrict__ rs,
    const float* __restrict__ cs, int K, int lda, int ldb, int ldc)
{
    __shared__ __align__(16) signed char As[128 * 64];
    __shared__ __align__(16) signed char Bs[128 * 64];

    int t    = threadIdx.x;
    int m0   = blockIdx.y * 128;
    int n0   = blockIdx.x * 128;
    int lane = t & 63;
    int w    = t >> 6;
    int wm   = (w >> 1) * 64;
    int wn   = (w & 1) * 64;
    int l15  = lane & 15;
    int quad = lane >> 4;

    int4v acc[4][4];
    #pragma unroll
    for (int i = 0; i < 4; i++)
        #pragma unroll
        for (int j = 0; j < 4; j++) { int4v z = {0,0,0,0}; acc[i][j] = z; }

    int srow = t >> 2;            // 0..63
    int scol = (t & 3) * 16;      // bytes within 64-B row
    signed char* lA0 = As + w * 1024;
    signed char* lA1 = As + 4096 + w * 1024;
    signed char* lB0 = Bs + w * 1024;
    signed char* lB1 = Bs + 4096 + w * 1024;

    for (int k0 = 0; k0 < K; k0 += 64) {
        const signed char* ga = A  + (size_t)(m0 + srow) * lda + k0 + scol;
        const signed char* gb = Bm + (size_t)(n0 + srow) * ldb + k0 + scol;
        async_cp16(ga, lA0);
        async_cp16(ga + (size_t)64 * lda, lA1);
        async_cp16(gb, lB0);
        async_cp16(gb + (size_t)64 * ldb, lB1);
        __syncthreads();

        int4v af[4], bf[4];
        #pragma unroll
        for (int i = 0; i < 4; i++) {
            af[i] = *(const int4v*)&As[(wm + i*16 + l15) * 64 + quad * 16];
            bf[i] = *(const int4v*)&Bs[(wn + i*16 + l15) * 64 + quad * 16];
        }
        #pragma unroll
        for (int i = 0; i < 4; i++)
            #pragma unroll
            for (int j = 0; j < 4; j++)
                acc[i][j] = __builtin_amdgcn_mfma_i32_16x16x64_i8(af[i], bf[j], acc[i][j], 0, 0, 0);
        __syncthreads();
    }

    #pragma unroll
    for (int i = 0; i < 4; i++) {
        #pragma unroll
        for (int j = 0; j < 4; j++) {
            #pragma unroll
            for (int r = 0; r < 4; r++) {
                int row = m0 + wm + i*16 + quad*4 + r;
                int col = n0 + wn + j*16 + l15;
                float v = (float)acc[i][j][r];
                if (MODE == 3) v *= rs[row] * cs[col];
                C[(size_t)row * ldc + col] = v;
            }
        }
    }
}

// --------------------------- K4: dequant + bias + rope + pack ---------------
__global__ __launch_bounds__(256) void derope_k(
    const float* __restrict__ Y, const float* __restrict__ sx,
    const float* __restrict__ sq, const float* __restrict__ bq,
    const float* __restrict__ sk, const float* __restrict__ bk,
    const float* __restrict__ sv, const float* __restrict__ bv,
    const float* __restrict__ cosb, const float* __restrict__ sinb,
    unsigned short* __restrict__ Q, unsigned short* __restrict__ Kb,
    unsigned short* __restrict__ Vt)
{
    const float qs = 0.08838834764831845f;   // 1/sqrt(HD) folded into Q
    int r = blockIdx.x;               // (b,s)
    int b = r >> 10;
    int s = r & (S_ - 1);
    float sxr = sx[r];
    const float* yr = Y + (size_t)r * NQKV;
    int t = threadIdx.x;

    for (int p = t; p < H_ * 64; p += 256) {
        int h = p >> 6, d = p & 63;
        int ca = h * HD_ + d;
        float a  = yr[ca]      * sxr * sq[ca]      + bq[ca];
        float b2 = yr[ca + 64] * sxr * sq[ca + 64] + bq[ca + 64];
        float c  = cosb[s * HD_ + d], sn = sinb[s * HD_ + d];
        size_t base = (((size_t)(b * H_ + h)) * S_ + s) * HD_;
        Q[base + d]      = f2bf((a * c - b2 * sn) * qs);
        Q[base + d + 64] = f2bf((b2 * c + a * sn) * qs);
    }
    for (int p = t; p < KV_ * 64; p += 256) {
        int kv = p >> 6, d = p & 63;
        int ci = kv * HD_ + d;
        int ca = H_ * HD_ + ci;
        float a  = yr[ca]      * sxr * sk[ci]      + bk[ci];
        float b2 = yr[ca + 64] * sxr * sk[ci + 64] + bk[ci + 64];
        float c  = cosb[s * HD_ + d], sn = sinb[s * HD_ + d];
        size_t base = (((size_t)(b * KV_ + kv)) * S_ + s) * HD_;
        Kb[base + d]      = f2bf(a * c - b2 * sn);
        Kb[base + d + 64] = f2bf(b2 * c + a * sn);
    }
    for (int p = t; p < KV_ * HD_; p += 256) {
        int kv = p >> 7, d = p & 127;
        int ci = kv * HD_ + d;
        int ca = H_ * HD_ + KV_ * HD_ + ci;
        float v = yr[ca] * sxr * sv[ci] + bv[ci];
        size_t idx = (((size_t)(b * KV_ + kv)) * HD_ + d) * S_ + s;
        Vt[idx] = f2bf(v);               // V^T (b,kv,hd,s)
    }
}

// --------------------------- K5: fused flash attention v2 -------------------
// Block = (b*H+h, q-tile of 64). 4 waves; wave w owns q rows w*16..w*16+15.
// K-tile 64. Padded LDS tiles staged via coalesced global loads + ds_write
// (conflict-free frag reads). P reuses the K buffer.
__global__ __launch_bounds__(256) void flash_attn_k(
    const unsigned short* __restrict__ Qg,   // (B,H,S,HD) bf16, *1/sqrt(HD)
    const unsigned short* __restrict__ Kg,   // (B,KV,S,HD) bf16
    const unsigned short* __restrict__ Vg,   // (B,KV,HD,S) bf16
    float* __restrict__ O)                   // (B*S, H*HD) fp32
{
    __shared__ __align__(16) unsigned short Ks[64 * KSTR];    // 16.9 KB; holds P later
    __shared__ __align__(16) unsigned short Vs[HD_ * VSTR];   // 17.4 KB

    int pair = blockIdx.x;              // b*H + h
    int qt   = 15 - blockIdx.y;         // big q-tiles dispatched first
    int b    = pair >> 5;
    int kv   = (pair & 31) >> 2;

    const unsigned short* Qb = Qg + ((size_t)pair * S_ + qt * 64) * HD_;
    const unsigned short* Kbp = Kg + ((size_t)(b * KV_ + kv)) * (S_ * HD_);
    const unsigned short* Vb = Vg + ((size_t)(b * KV_ + kv)) * (HD_ * S_);

    int t    = threadIdx.x;
    int lane = t & 63;
    int w    = t >> 6;
    int l15  = lane & 15;
    int quad = lane >> 4;

    // Q A-frags, loaded once: row w*16+l15, k = ks*32 + quad*8 + j
    short8 qf[4];
    #pragma unroll
    for (int ks = 0; ks < 4; ks++)
        qf[ks] = *(const short8*)(Qb + (size_t)(w*16 + l15) * HD_ + ks*32 + quad*8);

    f32x4 oacc[8];
    #pragma unroll
    for (int n = 0; n < 8; n++) { f32x4 z = {0.f,0.f,0.f,0.f}; oacc[n] = z; }
    float mrow[4], lrow[4];
    #pragma unroll
    for (int r = 0; r < 4; r++) { mrow[r] = -1e30f; lrow[r] = 0.f; }

    // staging thread mapping (256 threads):
    int kr4 = t >> 4, kc = t & 15;      // K: 16 rows/pass x 16 chunks, 4 passes
    int vr4 = t >> 3, vc = t & 7;       // V: 32 rows/pass x 8 chunks, 4 passes

    for (int j = 0; j <= qt; ++j) {
        int k0 = j * 64;
        __syncthreads();   // prior iter's P/V reads complete before overwrite

        // ---- stage K tile (64 k-rows x 128 hd) and V^T tile (128 hd x 64 k)
        #pragma unroll
        for (int p = 0; p < 4; ++p) {
            int krow = p * 16 + kr4;
            short8 kd = *(const short8*)(Kbp + (size_t)(k0 + krow) * HD_ + kc * 8);
            *(short8*)&Ks[krow * KSTR + kc * 8] = kd;
            int vrow = p * 32 + vr4;
            short8 vd = *(const short8*)(Vb + (size_t)vrow * S_ + k0 + vc * 8);
            *(short8*)&Vs[vrow * VSTR + vc * 8] = vd;
        }
        __syncthreads();

        // ---- S = Q * K^T   (16 q x 64 k per wave; C-layout col=l15,row=quad*4+r)
        f32x4 sacc[4];
        #pragma unroll
        for (int n = 0; n < 4; n++) { f32x4 z = {0.f,0.f,0.f,0.f}; sacc[n] = z; }
        #pragma unroll
        for (int n = 0; n < 4; n++) {
            #pragma unroll
            for (int ks = 0; ks < 4; ks++) {
                short8 kf = *(const short8*)&Ks[(n*16 + l15) * KSTR + ks*32 + quad*8];
                sacc[n] = __builtin_amdgcn_mfma_f32_16x16x32_bf16(qf[ks], kf, sacc[n], 0, 0, 0);
            }
        }

        // ---- causal mask on the diagonal tile
        if (j == qt) {
            #pragma unroll
            for (int n = 0; n < 4; n++)
                #pragma unroll
                for (int r = 0; r < 4; r++) {
                    int qrow = w*16 + quad*4 + r;
                    int kcol = n*16 + l15;
                    if (kcol > qrow) sacc[n][r] = -1e30f;
                }
        }

        // ---- online softmax update (row = quad*4+r; reduce over 16-lane group)
        #pragma unroll
        for (int r = 0; r < 4; r++) {
            float mx = fmaxf(fmaxf(sacc[0][r], sacc[1][r]), fmaxf(sacc[2][r], sacc[3][r]));
            mx = fmaxf(mx, __shfl_xor(mx, 1, 64));
            mx = fmaxf(mx, __shfl_xor(mx, 2, 64));
            mx = fmaxf(mx, __shfl_xor(mx, 4, 64));
            mx = fmaxf(mx, __shfl_xor(mx, 8, 64));
            float mnew = fmaxf(mrow[r], mx);
            float alpha = __expf(mrow[r] - mnew);
            mrow[r] = mnew;
            float s = 0.f;
            #pragma unroll
            for (int n = 0; n < 4; n++) {
                float e = __expf(sacc[n][r] - mnew);
                sacc[n][r] = e;
                s += e;
            }
            s += __shfl_xor(s, 1, 64);
            s += __shfl_xor(s, 2, 64);
            s += __shfl_xor(s, 4, 64);
            s += __shfl_xor(s, 8, 64);
            lrow[r] = lrow[r] * alpha + s;
            #pragma unroll
            for (int n = 0; n < 8; n++) oacc[n][r] *= alpha;
        }

        __syncthreads();   // all waves done reading Ks before P overwrites it

        // ---- P (bf16) -> LDS (Ks region, stride KSTR), wave-private q band
        unsigned short* Ps = Ks;
        #pragma unroll
        for (int n = 0; n < 4; n++)
            #pragma unroll
            for (int r = 0; r < 4; r++)
                Ps[(w*16 + quad*4 + r) * KSTR + n*16 + l15] = f2bf(sacc[n][r]);

        // ---- O += P * V  (pf from own band — in-wave dependency only)
        short8 pf[2];
        #pragma unroll
        for (int ks = 0; ks < 2; ks++)
            pf[ks] = *(const short8*)&Ps[(w*16 + l15) * KSTR + ks*32 + quad*8];
        #pragma unroll
        for (int n = 0; n < 8; n++) {
            #pragma unroll
            for (int ks = 0; ks < 2; ks++) {
                short8 vf = *(const short8*)&Vs[(n*16 + l15) * VSTR + ks*32 + quad*8];
                oacc[n] = __builtin_amdgcn_mfma_f32_16x16x32_bf16(pf[ks], vf, oacc[n], 0, 0, 0);
            }
        }
    }

    // ---- epilogue: normalize and store
    float* Ob = O + ((size_t)(b * S_ + qt * 64)) * (H_*HD_) + (pair & 31) * HD_;
    #pragma unroll
    for (int r = 0; r < 4; r++) {
        float inv = 1.0f / lrow[r];
        int row = w*16 + quad*4 + r;
        #pragma unroll
        for (int n = 0; n < 8; n++)
            Ob[(size_t)row * (H_*HD_) + n*16 + l15] = oacc[n][r] * inv;
    }
}

// ---------------------------------------------------------------------------
extern "C" void kernel_launch(void* const* d_in, const int* in_sizes, int n_in,
                              void* d_out, int out_size, void* d_ws, size_t ws_size,
                              hipStream_t stream)
{
    (void)in_sizes; (void)n_in; (void)out_size; (void)ws_size;
    const float* x    = (const float*)d_in[0];
    const float* cosb = (const float*)d_in[1];
    const float* sinb = (const float*)d_in[2];
    const int*   wq   = (const int*)d_in[3];
    const float* sq   = (const float*)d_in[4];
    const float* bq   = (const float*)d_in[5];
    const int*   wk   = (const int*)d_in[6];
    const float* sk   = (const float*)d_in[7];
    const float* bk   = (const float*)d_in[8];
    const int*   wv   = (const int*)d_in[9];
    const float* sv   = (const float*)d_in[10];
    const float* bv   = (const float*)d_in[11];
    const int*   wo   = (const int*)d_in[12];
    const float* so   = (const float*)d_in[13];
    float* out = (float*)d_out;
    char*  ws  = (char*)d_ws;

    // ws layout (~159.4 MB total)
    signed char*    Xi   = (signed char*)(ws + 0);              //  8.4 MB
    float*          Y    = (float*)(ws + 8388608ull);           // 50.3 MB
    signed char*    Wqkv = (signed char*)(ws + 58720256ull);    // 25.2 MB (Oi reuses)
    signed char*    Oi   = (signed char*)(ws + 58720256ull);
    signed char*    Wo   = (signed char*)(ws + 83886080ull);    // 16.8 MB
    unsigned short* Q    = (unsigned short*)(ws + 100663296ull);// 16.8 MB
    unsigned short* Kb   = (unsigned short*)(ws + 117440512ull);//  4.2 MB
    unsigned short* Vt   = (unsigned short*)(ws + 121634816ull);//  4.2 MB
    float*          O    = (float*)(ws + 125829120ull);         // 33.5 MB
    float*          sx   = (float*)(ws + 159383552ull);
    float*          sxo  = (float*)(ws + 159391744ull);

    // K1: quantize x rows -> int8 (K=4096)
    quantize_rows_k<<<dim3(NR), dim3(256), 0, stream>>>(x, Xi, sx);

    // K2: all weights -> int8, one launch (2621440 threads)
    convert_all_w<<<dim3(10240), dim3(256), 0, stream>>>(wq, wk, wv, wo, Wqkv, Wo);

    // K3: Y = Xi * Wqkv^T   (2048 x 6144, K=4096, int8 MFMA)
    gemm_i8_k<0><<<dim3(48,16,1), dim3(256), 0, stream>>>(
        Xi, Wqkv, Y, nullptr, nullptr, D_, D_, D_, NQKV);

    // K4: dequant + rope + pack (Q pre-scaled by 1/sqrt(HD))
    derope_k<<<dim3(NR), dim3(256), 0, stream>>>(
        Y, sx, sq, bq, sk, bk, sv, bv, cosb, sinb, Q, Kb, Vt);

    // K5: fused flash attention  (64 pairs x 16 q-tiles of 64)
    flash_attn_k<<<dim3(64, 16), dim3(256), 0, stream>>>(Q, Kb, Vt, O);

    // K6: quantize attention output rows -> int8 (K=4096)
    quantize_rows_k<<<dim3(NR), dim3(256), 0, stream>>>(O, Oi, sxo);

    // K7: out = float(Oi * Wo^T) * sxo[row] * so[col]  (int8 MFMA)
    gemm_i8_k<3><<<dim3(32,16,1), dim3(256), 0, stream>>>(
        Oi, Wo, out, sxo, so, D_, D_, D_, D_);
}

// Round 7
// 428.526 us; speedup vs baseline: 2.9562x; 1.0332x over previous
//
#include <hip/hip_runtime.h>

// ---------------------------------------------------------------------------
// GroupedQueryAttention: int8 dynamic-quant QKV proj + RoPE + causal GQA + O proj
// B=2 S=1024 D=4096 H=32 KV=8 HD=128 GROUP=4
//
// R7: gemm_i8_k rebuilt — BK=128 (32 K-iters, half the barrier drains) with
// XOR-swizzled LDS tiles (chunk (m,kc) stored at col kc^(m&7)): frag reads
// become 2-way bank-aliased (free) while global_load_lds dest stays lane-
// contiguous and sources stay row-contiguous. Flash/derope/quant unchanged.
// ---------------------------------------------------------------------------

#define B_   2
#define S_   1024
#define D_   4096
#define H_   32
#define KV_  8
#define HD_  128
#define NR   (B_ * S_)            // 2048 rows
#define NQKV (H_*HD_ + 2*KV_*HD_) // 6144

#define KSTR 132                  // flash K/P tile row stride (shorts)
#define VSTR 68                   // flash V tile row stride (shorts)

typedef __attribute__((ext_vector_type(8))) short  short8;
typedef __attribute__((ext_vector_type(4))) float  f32x4;
typedef __attribute__((ext_vector_type(4))) int    int4v;

static __device__ __forceinline__ unsigned short f2bf(float f) {
    unsigned u = __builtin_bit_cast(unsigned, f);
    u += 0x7fffu + ((u >> 16) & 1u);     // round-to-nearest-even
    return (unsigned short)(u >> 16);
}

// async global->LDS, 16 B per lane. LDS dest = wave-uniform base + lane*16;
// global source is per-lane.
static __device__ __forceinline__ void async_cp16(const void* g, void* l) {
    __builtin_amdgcn_global_load_lds(
        (const __attribute__((address_space(1))) void*)g,
        (__attribute__((address_space(3))) void*)l, 16, 0, 0);
}

// --------------------------- K1/K6: row quantization (fp32 -> int8) ---------
__global__ __launch_bounds__(256) void quantize_rows_k(
    const float* __restrict__ X, signed char* __restrict__ Xq,
    float* __restrict__ sx_out)
{
    int row = blockIdx.x;
    const f32x4* xr = (const f32x4*)(X + (size_t)row * 4096);
    int t = threadIdx.x;

    f32x4 v[4];
    #pragma unroll
    for (int i = 0; i < 4; i++) v[i] = xr[t + i * 256];

    float m = 0.f;
    #pragma unroll
    for (int i = 0; i < 4; i++)
        #pragma unroll
        for (int j = 0; j < 4; j++) m = fmaxf(m, fabsf(v[i][j]));
    #pragma unroll
    for (int off = 32; off > 0; off >>= 1) m = fmaxf(m, __shfl_down(m, off, 64));
    __shared__ float red[4];
    if ((t & 63) == 0) red[t >> 6] = m;
    __syncthreads();
    float mm = fmaxf(fmaxf(red[0], red[1]), fmaxf(red[2], red[3]));
    float sx = mm / 127.0f;
    if (sx == 0.f) sx = 1.f;
    if (t == 0) sx_out[row] = sx;

    int* dst = (int*)(Xq + (size_t)row * 4096);
    #pragma unroll
    for (int i = 0; i < 4; i++) {
        int o = 0;
        #pragma unroll
        for (int j = 0; j < 4; j++) {
            float q = rintf(v[i][j] / sx);
            q = fminf(fmaxf(q, -127.f), 127.f);
            o |= (((int)q) & 0xff) << (j * 8);
        }
        dst[t + i * 256] = o;
    }
}

// --------------------------- K2: all weights -> int8, one launch ------------
__global__ __launch_bounds__(256) void convert_all_w(
    const int* __restrict__ wq, const int* __restrict__ wk,
    const int* __restrict__ wv, const int* __restrict__ wo,
    signed char* __restrict__ Wqkv, signed char* __restrict__ Wo)
{
    int i = blockIdx.x * 256 + threadIdx.x;
    const int* src;
    signed char* dst;
    if (i < 1048576)      { src = wq + (size_t)i * 16;              dst = Wqkv + (size_t)i * 16; }
    else if (i < 1310720) { int j = i - 1048576; src = wk + (size_t)j * 16; dst = Wqkv + 16777216 + (size_t)j * 16; }
    else if (i < 1572864) { int j = i - 1310720; src = wv + (size_t)j * 16; dst = Wqkv + 20971520 + (size_t)j * 16; }
    else                  { int j = i - 1572864; src = wo + (size_t)j * 16; dst = Wo + (size_t)j * 16; }
    const int4v* s4 = (const int4v*)src;
    int4v a = s4[0], b = s4[1], c = s4[2], d = s4[3];
    int4v o;
    o[0] = (a[0]&0xff) | ((a[1]&0xff)<<8) | ((a[2]&0xff)<<16) | ((a[3]&0xff)<<24);
    o[1] = (b[0]&0xff) | ((b[1]&0xff)<<8) | ((b[2]&0xff)<<16) | ((b[3]&0xff)<<24);
    o[2] = (c[0]&0xff) | ((c[1]&0xff)<<8) | ((c[2]&0xff)<<16) | ((c[3]&0xff)<<24);
    o[3] = (d[0]&0xff) | ((d[1]&0xff)<<8) | ((d[2]&0xff)<<16) | ((d[3]&0xff)<<24);
    *(int4v*)dst = o;
}

// --------------------------- int8 GEMM: C = A * B^T (i8 -> i32 -> f32) ------
// BK=128, XOR-swizzled LDS: 16-B chunk (m, kc) lives at (m*8 + (kc^(m&7)))*16.
// MODE 0: C = float(acc).   MODE 3: C = float(acc) * rs[row] * cs[col].
template<int MODE>
__global__ __launch_bounds__(256) void gemm_i8_k(
    const signed char* __restrict__ A, const signed char* __restrict__ Bm,
    float* __restrict__ C, const float* __restrict__ rs,
    const float* __restrict__ cs, int K, int lda, int ldb, int ldc)
{
    __shared__ __align__(16) signed char As[128 * 128];   // 16 KB
    __shared__ __align__(16) signed char Bs[128 * 128];   // 16 KB

    int t    = threadIdx.x;
    int m0   = blockIdx.y * 128;
    int n0   = blockIdx.x * 128;
    int lane = t & 63;
    int w    = t >> 6;
    int wm   = (w >> 1) * 64;
    int wn   = (w & 1) * 64;
    int l15  = lane & 15;
    int quad = lane >> 4;

    int4v acc[4][4];
    #pragma unroll
    for (int i = 0; i < 4; i++)
        #pragma unroll
        for (int j = 0; j < 4; j++) { int4v z = {0,0,0,0}; acc[i][j] = z; }

    // staging: chunk c = p*256 + w*64 + lane; m = c>>3, stored col = c&7,
    // source kc = (c&7) ^ (m&7).  Dest runs are lane-contiguous (wave-uniform
    // base (p*256+w*64)*16); sources are row-contiguous per 8 lanes.
    int cw   = w * 64 + lane;            // chunk within pass, p adds 256
    int smr  = cw >> 3;                  // m (rows 0..31 for p=0; +32/pass)
    int scol = cw & 7;

    for (int k0 = 0; k0 < K; k0 += 128) {
        #pragma unroll
        for (int p = 0; p < 4; ++p) {
            int m  = p * 32 + smr;
            int kc = scol ^ (m & 7);
            const signed char* ga = A  + (size_t)(m0 + m) * lda + k0 + kc * 16;
            const signed char* gb = Bm + (size_t)(n0 + m) * ldb + k0 + kc * 16;
            async_cp16(ga, As + (p * 256 + w * 64) * 16);
            async_cp16(gb, Bs + (p * 256 + w * 64) * 16);
        }
        __syncthreads();

        #pragma unroll
        for (int ks = 0; ks < 2; ks++) {
            int4v af[4], bf[4];
            #pragma unroll
            for (int i = 0; i < 4; i++) {
                int ra = wm + i*16 + l15;
                int rb = wn + i*16 + l15;
                af[i] = *(const int4v*)&As[(ra * 8 + (((ks*4 + quad) ^ (ra & 7)))) * 16];
                bf[i] = *(const int4v*)&Bs[(rb * 8 + (((ks*4 + quad) ^ (rb & 7)))) * 16];
            }
            #pragma unroll
            for (int i = 0; i < 4; i++)
                #pragma unroll
                for (int j = 0; j < 4; j++)
                    acc[i][j] = __builtin_amdgcn_mfma_i32_16x16x64_i8(af[i], bf[j], acc[i][j], 0, 0, 0);
        }
        __syncthreads();
    }

    #pragma unroll
    for (int i = 0; i < 4; i++) {
        #pragma unroll
        for (int j = 0; j < 4; j++) {
            #pragma unroll
            for (int r = 0; r < 4; r++) {
                int row = m0 + wm + i*16 + quad*4 + r;
                int col = n0 + wn + j*16 + l15;
                float v = (float)acc[i][j][r];
                if (MODE == 3) v *= rs[row] * cs[col];
                C[(size_t)row * ldc + col] = v;
            }
        }
    }
}

// --------------------------- K4: dequant + bias + rope + pack ---------------
__global__ __launch_bounds__(256) void derope_k(
    const float* __restrict__ Y, const float* __restrict__ sx,
    const float* __restrict__ sq, const float* __restrict__ bq,
    const float* __restrict__ sk, const float* __restrict__ bk,
    const float* __restrict__ sv, const float* __restrict__ bv,
    const float* __restrict__ cosb, const float* __restrict__ sinb,
    unsigned short* __restrict__ Q, unsigned short* __restrict__ Kb,
    unsigned short* __restrict__ Vt)
{
    const float qs = 0.08838834764831845f;   // 1/sqrt(HD) folded into Q
    int r = blockIdx.x;               // (b,s)
    int b = r >> 10;
    int s = r & (S_ - 1);
    float sxr = sx[r];
    const float* yr = Y + (size_t)r * NQKV;
    int t = threadIdx.x;

    for (int p = t; p < H_ * 64; p += 256) {
        int h = p >> 6, d = p & 63;
        int ca = h * HD_ + d;
        float a  = yr[ca]      * sxr * sq[ca]      + bq[ca];
        float b2 = yr[ca + 64] * sxr * sq[ca + 64] + bq[ca + 64];
        float c  = cosb[s * HD_ + d], sn = sinb[s * HD_ + d];
        size_t base = (((size_t)(b * H_ + h)) * S_ + s) * HD_;
        Q[base + d]      = f2bf((a * c - b2 * sn) * qs);
        Q[base + d + 64] = f2bf((b2 * c + a * sn) * qs);
    }
    for (int p = t; p < KV_ * 64; p += 256) {
        int kv = p >> 6, d = p & 63;
        int ci = kv * HD_ + d;
        int ca = H_ * HD_ + ci;
        float a  = yr[ca]      * sxr * sk[ci]      + bk[ci];
        float b2 = yr[ca + 64] * sxr * sk[ci + 64] + bk[ci + 64];
        float c  = cosb[s * HD_ + d], sn = sinb[s * HD_ + d];
        size_t base = (((size_t)(b * KV_ + kv)) * S_ + s) * HD_;
        Kb[base + d]      = f2bf(a * c - b2 * sn);
        Kb[base + d + 64] = f2bf(b2 * c + a * sn);
    }
    for (int p = t; p < KV_ * HD_; p += 256) {
        int kv = p >> 7, d = p & 127;
        int ci = kv * HD_ + d;
        int ca = H_ * HD_ + KV_ * HD_ + ci;
        float v = yr[ca] * sxr * sv[ci] + bv[ci];
        size_t idx = (((size_t)(b * KV_ + kv)) * HD_ + d) * S_ + s;
        Vt[idx] = f2bf(v);               // V^T (b,kv,hd,s)
    }
}

// --------------------------- K5: fused flash attention v2 -------------------
__global__ __launch_bounds__(256) void flash_attn_k(
    const unsigned short* __restrict__ Qg,   // (B,H,S,HD) bf16, *1/sqrt(HD)
    const unsigned short* __restrict__ Kg,   // (B,KV,S,HD) bf16
    const unsigned short* __restrict__ Vg,   // (B,KV,HD,S) bf16
    float* __restrict__ O)                   // (B*S, H*HD) fp32
{
    __shared__ __align__(16) unsigned short Ks[64 * KSTR];    // 16.9 KB; holds P later
    __shared__ __align__(16) unsigned short Vs[HD_ * VSTR];   // 17.4 KB

    int pair = blockIdx.x;              // b*H + h
    int qt   = 15 - blockIdx.y;         // big q-tiles dispatched first
    int b    = pair >> 5;
    int kv   = (pair & 31) >> 2;

    const unsigned short* Qb = Qg + ((size_t)pair * S_ + qt * 64) * HD_;
    const unsigned short* Kbp = Kg + ((size_t)(b * KV_ + kv)) * (S_ * HD_);
    const unsigned short* Vb = Vg + ((size_t)(b * KV_ + kv)) * (HD_ * S_);

    int t    = threadIdx.x;
    int lane = t & 63;
    int w    = t >> 6;
    int l15  = lane & 15;
    int quad = lane >> 4;

    short8 qf[4];
    #pragma unroll
    for (int ks = 0; ks < 4; ks++)
        qf[ks] = *(const short8*)(Qb + (size_t)(w*16 + l15) * HD_ + ks*32 + quad*8);

    f32x4 oacc[8];
    #pragma unroll
    for (int n = 0; n < 8; n++) { f32x4 z = {0.f,0.f,0.f,0.f}; oacc[n] = z; }
    float mrow[4], lrow[4];
    #pragma unroll
    for (int r = 0; r < 4; r++) { mrow[r] = -1e30f; lrow[r] = 0.f; }

    int kr4 = t >> 4, kc = t & 15;      // K staging: 16 rows x 16 chunks, 4 passes
    int vr4 = t >> 3, vc = t & 7;       // V staging: 32 rows x 8 chunks, 4 passes

    for (int j = 0; j <= qt; ++j) {
        int k0 = j * 64;
        __syncthreads();

        #pragma unroll
        for (int p = 0; p < 4; ++p) {
            int krow = p * 16 + kr4;
            short8 kd = *(const short8*)(Kbp + (size_t)(k0 + krow) * HD_ + kc * 8);
            *(short8*)&Ks[krow * KSTR + kc * 8] = kd;
            int vrow = p * 32 + vr4;
            short8 vd = *(const short8*)(Vb + (size_t)vrow * S_ + k0 + vc * 8);
            *(short8*)&Vs[vrow * VSTR + vc * 8] = vd;
        }
        __syncthreads();

        f32x4 sacc[4];
        #pragma unroll
        for (int n = 0; n < 4; n++) { f32x4 z = {0.f,0.f,0.f,0.f}; sacc[n] = z; }
        #pragma unroll
        for (int n = 0; n < 4; n++) {
            #pragma unroll
            for (int ks = 0; ks < 4; ks++) {
                short8 kf = *(const short8*)&Ks[(n*16 + l15) * KSTR + ks*32 + quad*8];
                sacc[n] = __builtin_amdgcn_mfma_f32_16x16x32_bf16(qf[ks], kf, sacc[n], 0, 0, 0);
            }
        }

        if (j == qt) {
            #pragma unroll
            for (int n = 0; n < 4; n++)
                #pragma unroll
                for (int r = 0; r < 4; r++) {
                    int qrow = w*16 + quad*4 + r;
                    int kcol = n*16 + l15;
                    if (kcol > qrow) sacc[n][r] = -1e30f;
                }
        }

        #pragma unroll
        for (int r = 0; r < 4; r++) {
            float mx = fmaxf(fmaxf(sacc[0][r], sacc[1][r]), fmaxf(sacc[2][r], sacc[3][r]));
            mx = fmaxf(mx, __shfl_xor(mx, 1, 64));
            mx = fmaxf(mx, __shfl_xor(mx, 2, 64));
            mx = fmaxf(mx, __shfl_xor(mx, 4, 64));
            mx = fmaxf(mx, __shfl_xor(mx, 8, 64));
            float mnew = fmaxf(mrow[r], mx);
            float alpha = __expf(mrow[r] - mnew);
            mrow[r] = mnew;
            float s = 0.f;
            #pragma unroll
            for (int n = 0; n < 4; n++) {
                float e = __expf(sacc[n][r] - mnew);
                sacc[n][r] = e;
                s += e;
            }
            s += __shfl_xor(s, 1, 64);
            s += __shfl_xor(s, 2, 64);
            s += __shfl_xor(s, 4, 64);
            s += __shfl_xor(s, 8, 64);
            lrow[r] = lrow[r] * alpha + s;
            #pragma unroll
            for (int n = 0; n < 8; n++) oacc[n][r] *= alpha;
        }

        __syncthreads();

        unsigned short* Ps = Ks;
        #pragma unroll
        for (int n = 0; n < 4; n++)
            #pragma unroll
            for (int r = 0; r < 4; r++)
                Ps[(w*16 + quad*4 + r) * KSTR + n*16 + l15] = f2bf(sacc[n][r]);

        short8 pf[2];
        #pragma unroll
        for (int ks = 0; ks < 2; ks++)
            pf[ks] = *(const short8*)&Ps[(w*16 + l15) * KSTR + ks*32 + quad*8];
        #pragma unroll
        for (int n = 0; n < 8; n++) {
            #pragma unroll
            for (int ks = 0; ks < 2; ks++) {
                short8 vf = *(const short8*)&Vs[(n*16 + l15) * VSTR + ks*32 + quad*8];
                oacc[n] = __builtin_amdgcn_mfma_f32_16x16x32_bf16(pf[ks], vf, oacc[n], 0, 0, 0);
            }
        }
    }

    float* Ob = O + ((size_t)(b * S_ + qt * 64)) * (H_*HD_) + (pair & 31) * HD_;
    #pragma unroll
    for (int r = 0; r < 4; r++) {
        float inv = 1.0f / lrow[r];
        int row = w*16 + quad*4 + r;
        #pragma unroll
        for (int n = 0; n < 8; n++)
            Ob[(size_t)row * (H_*HD_) + n*16 + l15] = oacc[n][r] * inv;
    }
}

// ---------------------------------------------------------------------------
extern "C" void kernel_launch(void* const* d_in, const int* in_sizes, int n_in,
                              void* d_out, int out_size, void* d_ws, size_t ws_size,
                              hipStream_t stream)
{
    (void)in_sizes; (void)n_in; (void)out_size; (void)ws_size;
    const float* x    = (const float*)d_in[0];
    const float* cosb = (const float*)d_in[1];
    const float* sinb = (const float*)d_in[2];
    const int*   wq   = (const int*)d_in[3];
    const float* sq   = (const float*)d_in[4];
    const float* bq   = (const float*)d_in[5];
    const int*   wk   = (const int*)d_in[6];
    const float* sk   = (const float*)d_in[7];
    const float* bk   = (const float*)d_in[8];
    const int*   wv   = (const int*)d_in[9];
    const float* sv   = (const float*)d_in[10];
    const float* bv   = (const float*)d_in[11];
    const int*   wo   = (const int*)d_in[12];
    const float* so   = (const float*)d_in[13];
    float* out = (float*)d_out;
    char*  ws  = (char*)d_ws;

    // ws layout (~159.4 MB total)
    signed char*    Xi   = (signed char*)(ws + 0);              //  8.4 MB
    float*          Y    = (float*)(ws + 8388608ull);           // 50.3 MB
    signed char*    Wqkv = (signed char*)(ws + 58720256ull);    // 25.2 MB (Oi reuses)
    signed char*    Oi   = (signed char*)(ws + 58720256ull);
    signed char*    Wo   = (signed char*)(ws + 83886080ull);    // 16.8 MB
    unsigned short* Q    = (unsigned short*)(ws + 100663296ull);// 16.8 MB
    unsigned short* Kb   = (unsigned short*)(ws + 117440512ull);//  4.2 MB
    unsigned short* Vt   = (unsigned short*)(ws + 121634816ull);//  4.2 MB
    float*          O    = (float*)(ws + 125829120ull);         // 33.5 MB
    float*          sx   = (float*)(ws + 159383552ull);
    float*          sxo  = (float*)(ws + 159391744ull);

    // K1: quantize x rows -> int8 (K=4096)
    quantize_rows_k<<<dim3(NR), dim3(256), 0, stream>>>(x, Xi, sx);

    // K2: all weights -> int8, one launch
    convert_all_w<<<dim3(10240), dim3(256), 0, stream>>>(wq, wk, wv, wo, Wqkv, Wo);

    // K3: Y = Xi * Wqkv^T   (2048 x 6144, K=4096, int8 MFMA, BK=128 swizzled)
    gemm_i8_k<0><<<dim3(48,16,1), dim3(256), 0, stream>>>(
        Xi, Wqkv, Y, nullptr, nullptr, D_, D_, D_, NQKV);

    // K4: dequant + rope + pack (Q pre-scaled by 1/sqrt(HD))
    derope_k<<<dim3(NR), dim3(256), 0, stream>>>(
        Y, sx, sq, bq, sk, bk, sv, bv, cosb, sinb, Q, Kb, Vt);

    // K5: fused flash attention  (64 pairs x 16 q-tiles of 64)
    flash_attn_k<<<dim3(64, 16), dim3(256), 0, stream>>>(Q, Kb, Vt, O);

    // K6: quantize attention output rows -> int8 (K=4096)
    quantize_rows_k<<<dim3(NR), dim3(256), 0, stream>>>(O, Oi, sxo);

    // K7: out = float(Oi * Wo^T) * sxo[row] * so[col]  (int8 MFMA, BK=128)
    gemm_i8_k<3><<<dim3(32,16,1), dim3(256), 0, stream>>>(
        Oi, Wo, out, sxo, so, D_, D_, D_, D_);
}

// Round 8
// 412.627 us; speedup vs baseline: 3.0701x; 1.0385x over previous
//
#include <hip/hip_runtime.h>

// ---------------------------------------------------------------------------
// GroupedQueryAttention: int8 dynamic-quant QKV proj + RoPE + causal GQA + O proj
// B=2 S=1024 D=4096 H=32 KV=8 HD=128 GROUP=4
//
// R8: flash v3 — paired q-tiles (tp,15-tp) per block: every block does exactly
// 9 K-128 tiles (no tail imbalance); K-tile 128 halves barriers + softmax
// rescale; XOR-swizzled 64 KB LDS (2-way bank alias = free); register
// prefetch of next K/V tile across the staging barrier. gemm/derope/quant
// unchanged from R7.
// ---------------------------------------------------------------------------

#define B_   2
#define S_   1024
#define D_   4096
#define H_   32
#define KV_  8
#define HD_  128
#define NR   (B_ * S_)            // 2048 rows
#define NQKV (H_*HD_ + 2*KV_*HD_) // 6144

typedef __attribute__((ext_vector_type(8))) short  short8;
typedef __attribute__((ext_vector_type(4))) float  f32x4;
typedef __attribute__((ext_vector_type(4))) int    int4v;

// 16-B chunk swizzle: chunk c (0..15) of row r stored at column FA_SW(c,r)
#define FA_SW(c, r) (((c) & 8) | (((c) & 7) ^ ((r) & 7)))

static __device__ __forceinline__ unsigned short f2bf(float f) {
    unsigned u = __builtin_bit_cast(unsigned, f);
    u += 0x7fffu + ((u >> 16) & 1u);     // round-to-nearest-even
    return (unsigned short)(u >> 16);
}

// async global->LDS, 16 B per lane. LDS dest = wave-uniform base + lane*16.
static __device__ __forceinline__ void async_cp16(const void* g, void* l) {
    __builtin_amdgcn_global_load_lds(
        (const __attribute__((address_space(1))) void*)g,
        (__attribute__((address_space(3))) void*)l, 16, 0, 0);
}

// --------------------------- K1/K6: row quantization (fp32 -> int8) ---------
__global__ __launch_bounds__(256) void quantize_rows_k(
    const float* __restrict__ X, signed char* __restrict__ Xq,
    float* __restrict__ sx_out)
{
    int row = blockIdx.x;
    const f32x4* xr = (const f32x4*)(X + (size_t)row * 4096);
    int t = threadIdx.x;

    f32x4 v[4];
    #pragma unroll
    for (int i = 0; i < 4; i++) v[i] = xr[t + i * 256];

    float m = 0.f;
    #pragma unroll
    for (int i = 0; i < 4; i++)
        #pragma unroll
        for (int j = 0; j < 4; j++) m = fmaxf(m, fabsf(v[i][j]));
    #pragma unroll
    for (int off = 32; off > 0; off >>= 1) m = fmaxf(m, __shfl_down(m, off, 64));
    __shared__ float red[4];
    if ((t & 63) == 0) red[t >> 6] = m;
    __syncthreads();
    float mm = fmaxf(fmaxf(red[0], red[1]), fmaxf(red[2], red[3]));
    float sx = mm / 127.0f;
    if (sx == 0.f) sx = 1.f;
    if (t == 0) sx_out[row] = sx;

    int* dst = (int*)(Xq + (size_t)row * 4096);
    #pragma unroll
    for (int i = 0; i < 4; i++) {
        int o = 0;
        #pragma unroll
        for (int j = 0; j < 4; j++) {
            float q = rintf(v[i][j] / sx);
            q = fminf(fmaxf(q, -127.f), 127.f);
            o |= (((int)q) & 0xff) << (j * 8);
        }
        dst[t + i * 256] = o;
    }
}

// --------------------------- K2: all weights -> int8, one launch ------------
__global__ __launch_bounds__(256) void convert_all_w(
    const int* __restrict__ wq, const int* __restrict__ wk,
    const int* __restrict__ wv, const int* __restrict__ wo,
    signed char* __restrict__ Wqkv, signed char* __restrict__ Wo)
{
    int i = blockIdx.x * 256 + threadIdx.x;
    const int* src;
    signed char* dst;
    if (i < 1048576)      { src = wq + (size_t)i * 16;              dst = Wqkv + (size_t)i * 16; }
    else if (i < 1310720) { int j = i - 1048576; src = wk + (size_t)j * 16; dst = Wqkv + 16777216 + (size_t)j * 16; }
    else if (i < 1572864) { int j = i - 1310720; src = wv + (size_t)j * 16; dst = Wqkv + 20971520 + (size_t)j * 16; }
    else                  { int j = i - 1572864; src = wo + (size_t)j * 16; dst = Wo + (size_t)j * 16; }
    const int4v* s4 = (const int4v*)src;
    int4v a = s4[0], b = s4[1], c = s4[2], d = s4[3];
    int4v o;
    o[0] = (a[0]&0xff) | ((a[1]&0xff)<<8) | ((a[2]&0xff)<<16) | ((a[3]&0xff)<<24);
    o[1] = (b[0]&0xff) | ((b[1]&0xff)<<8) | ((b[2]&0xff)<<16) | ((b[3]&0xff)<<24);
    o[2] = (c[0]&0xff) | ((c[1]&0xff)<<8) | ((c[2]&0xff)<<16) | ((c[3]&0xff)<<24);
    o[3] = (d[0]&0xff) | ((d[1]&0xff)<<8) | ((d[2]&0xff)<<16) | ((d[3]&0xff)<<24);
    *(int4v*)dst = o;
}

// --------------------------- int8 GEMM: C = A * B^T (i8 -> i32 -> f32) ------
// BK=128, XOR-swizzled LDS: 16-B chunk (m, kc) lives at (m*8 + (kc^(m&7)))*16.
// MODE 0: C = float(acc).   MODE 3: C = float(acc) * rs[row] * cs[col].
template<int MODE>
__global__ __launch_bounds__(256) void gemm_i8_k(
    const signed char* __restrict__ A, const signed char* __restrict__ Bm,
    float* __restrict__ C, const float* __restrict__ rs,
    const float* __restrict__ cs, int K, int lda, int ldb, int ldc)
{
    __shared__ __align__(16) signed char As[128 * 128];   // 16 KB
    __shared__ __align__(16) signed char Bs[128 * 128];   // 16 KB

    int t    = threadIdx.x;
    int m0   = blockIdx.y * 128;
    int n0   = blockIdx.x * 128;
    int lane = t & 63;
    int w    = t >> 6;
    int wm   = (w >> 1) * 64;
    int wn   = (w & 1) * 64;
    int l15  = lane & 15;
    int quad = lane >> 4;

    int4v acc[4][4];
    #pragma unroll
    for (int i = 0; i < 4; i++)
        #pragma unroll
        for (int j = 0; j < 4; j++) { int4v z = {0,0,0,0}; acc[i][j] = z; }

    int cw   = w * 64 + lane;
    int smr  = cw >> 3;
    int scol = cw & 7;

    for (int k0 = 0; k0 < K; k0 += 128) {
        #pragma unroll
        for (int p = 0; p < 4; ++p) {
            int m  = p * 32 + smr;
            int kc = scol ^ (m & 7);
            const signed char* ga = A  + (size_t)(m0 + m) * lda + k0 + kc * 16;
            const signed char* gb = Bm + (size_t)(n0 + m) * ldb + k0 + kc * 16;
            async_cp16(ga, As + (p * 256 + w * 64) * 16);
            async_cp16(gb, Bs + (p * 256 + w * 64) * 16);
        }
        __syncthreads();

        #pragma unroll
        for (int ks = 0; ks < 2; ks++) {
            int4v af[4], bf[4];
            #pragma unroll
            for (int i = 0; i < 4; i++) {
                int ra = wm + i*16 + l15;
                int rb = wn + i*16 + l15;
                af[i] = *(const int4v*)&As[(ra * 8 + (((ks*4 + quad) ^ (ra & 7)))) * 16];
                bf[i] = *(const int4v*)&Bs[(rb * 8 + (((ks*4 + quad) ^ (rb & 7)))) * 16];
            }
            #pragma unroll
            for (int i = 0; i < 4; i++)
                #pragma unroll
                for (int j = 0; j < 4; j++)
                    acc[i][j] = __builtin_amdgcn_mfma_i32_16x16x64_i8(af[i], bf[j], acc[i][j], 0, 0, 0);
        }
        __syncthreads();
    }

    #pragma unroll
    for (int i = 0; i < 4; i++) {
        #pragma unroll
        for (int j = 0; j < 4; j++) {
            #pragma unroll
            for (int r = 0; r < 4; r++) {
                int row = m0 + wm + i*16 + quad*4 + r;
                int col = n0 + wn + j*16 + l15;
                float v = (float)acc[i][j][r];
                if (MODE == 3) v *= rs[row] * cs[col];
                C[(size_t)row * ldc + col] = v;
            }
        }
    }
}

// --------------------------- K4: dequant + bias + rope + pack ---------------
__global__ __launch_bounds__(256) void derope_k(
    const float* __restrict__ Y, const float* __restrict__ sx,
    const float* __restrict__ sq, const float* __restrict__ bq,
    const float* __restrict__ sk, const float* __restrict__ bk,
    const float* __restrict__ sv, const float* __restrict__ bv,
    const float* __restrict__ cosb, const float* __restrict__ sinb,
    unsigned short* __restrict__ Q, unsigned short* __restrict__ Kb,
    unsigned short* __restrict__ Vt)
{
    const float qs = 0.08838834764831845f;   // 1/sqrt(HD) folded into Q
    int r = blockIdx.x;               // (b,s)
    int b = r >> 10;
    int s = r & (S_ - 1);
    float sxr = sx[r];
    const float* yr = Y + (size_t)r * NQKV;
    int t = threadIdx.x;

    for (int p = t; p < H_ * 64; p += 256) {
        int h = p >> 6, d = p & 63;
        int ca = h * HD_ + d;
        float a  = yr[ca]      * sxr * sq[ca]      + bq[ca];
        float b2 = yr[ca + 64] * sxr * sq[ca + 64] + bq[ca + 64];
        float c  = cosb[s * HD_ + d], sn = sinb[s * HD_ + d];
        size_t base = (((size_t)(b * H_ + h)) * S_ + s) * HD_;
        Q[base + d]      = f2bf((a * c - b2 * sn) * qs);
        Q[base + d + 64] = f2bf((b2 * c + a * sn) * qs);
    }
    for (int p = t; p < KV_ * 64; p += 256) {
        int kv = p >> 6, d = p & 63;
        int ci = kv * HD_ + d;
        int ca = H_ * HD_ + ci;
        float a  = yr[ca]      * sxr * sk[ci]      + bk[ci];
        float b2 = yr[ca + 64] * sxr * sk[ci + 64] + bk[ci + 64];
        float c  = cosb[s * HD_ + d], sn = sinb[s * HD_ + d];
        size_t base = (((size_t)(b * KV_ + kv)) * S_ + s) * HD_;
        Kb[base + d]      = f2bf(a * c - b2 * sn);
        Kb[base + d + 64] = f2bf(b2 * c + a * sn);
    }
    for (int p = t; p < KV_ * HD_; p += 256) {
        int kv = p >> 7, d = p & 127;
        int ci = kv * HD_ + d;
        int ca = H_ * HD_ + KV_ * HD_ + ci;
        float v = yr[ca] * sxr * sv[ci] + bv[ci];
        size_t idx = (((size_t)(b * KV_ + kv)) * HD_ + d) * S_ + s;
        Vt[idx] = f2bf(v);               // V^T (b,kv,hd,s)
    }
}

// --------------------------- K5: fused flash attention v3 -------------------
// Block = (pair, tp): processes q-tiles qt=tp then qt=15-tp (64 rows each) ->
// exactly 9 K-128 tiles per block (balanced). 4 waves; wave w owns q rows
// w*16..+15. XOR-swizzled 32 KB K tile (reused for P) + 32 KB V^T tile.
// Register prefetch of next tile across the staging barrier.
__global__ __launch_bounds__(256, 2) void flash_attn_k(
    const unsigned short* __restrict__ Qg,   // (B,H,S,HD) bf16, *1/sqrt(HD)
    const unsigned short* __restrict__ Kg,   // (B,KV,S,HD) bf16
    const unsigned short* __restrict__ Vg,   // (B,KV,HD,S) bf16
    float* __restrict__ O)                   // (B*S, H*HD) fp32
{
    __shared__ __align__(16) unsigned short Ks[128 * 128];   // 32 KB; holds P later
    __shared__ __align__(16) unsigned short Vs[128 * 128];   // 32 KB

    int pair = blockIdx.x;              // b*H + h
    int tp   = blockIdx.y;              // 0..7 -> q-tiles {tp, 15-tp}
    int b    = pair >> 5;
    int kv   = (pair & 31) >> 2;

    const unsigned short* Kbp = Kg + ((size_t)(b * KV_ + kv)) * (S_ * HD_);
    const unsigned short* Vb  = Vg + ((size_t)(b * KV_ + kv)) * (HD_ * S_);

    int t    = threadIdx.x;
    int lane = t & 63;
    int w    = t >> 6;
    int l15  = lane & 15;
    int quad = lane >> 4;
    int trow = t >> 4;                  // staging row within 16-row pass
    int tcol = t & 15;                  // staging 16-B chunk

    // initial prefetch of tile k0=0 (used by phase 0, iter 0)
    short8 kreg[8], vreg[8];
    #pragma unroll
    for (int p = 0; p < 8; ++p) {
        int row = p * 16 + trow;
        kreg[p] = *(const short8*)(Kbp + (size_t)row * HD_ + tcol * 8);
        vreg[p] = *(const short8*)(Vb  + (size_t)row * S_  + tcol * 8);
    }

    #pragma unroll
    for (int phase = 0; phase < 2; ++phase) {
        int qt   = phase ? (15 - tp) : tp;
        int n128 = (qt + 2) >> 1;
        const unsigned short* Qb = Qg + ((size_t)pair * S_ + qt * 64) * HD_;

        short8 qf[4];
        #pragma unroll
        for (int ks = 0; ks < 4; ks++)
            qf[ks] = *(const short8*)(Qb + (size_t)(w*16 + l15) * HD_ + ks*32 + quad*8);

        f32x4 oacc[8];
        #pragma unroll
        for (int n = 0; n < 8; n++) { f32x4 z = {0.f,0.f,0.f,0.f}; oacc[n] = z; }
        float mrow[4], lrow[4];
        #pragma unroll
        for (int r = 0; r < 4; r++) { mrow[r] = -1e30f; lrow[r] = 0.f; }

        for (int j = 0; j < n128; ++j) {
            __syncthreads();   // prior tile's LDS reads complete

            // ---- commit prefetched tile to LDS (swizzled)
            #pragma unroll
            for (int p = 0; p < 8; ++p) {
                int row = p * 16 + trow;
                int c = FA_SW(tcol, row);
                *(short8*)&Ks[row * 128 + c * 8] = kreg[p];
                *(short8*)&Vs[row * 128 + c * 8] = vreg[p];
            }
            __syncthreads();

            // ---- prefetch next tile (next j, or next phase's k0=0)
            int k0n = (j + 1 < n128) ? (j + 1) * 128 : (phase == 0 ? 0 : -1);
            if (k0n >= 0) {
                #pragma unroll
                for (int p = 0; p < 8; ++p) {
                    int row = p * 16 + trow;
                    kreg[p] = *(const short8*)(Kbp + (size_t)(k0n + row) * HD_ + tcol * 8);
                    vreg[p] = *(const short8*)(Vb  + (size_t)row * S_ + k0n + tcol * 8);
                }
            }

            // ---- S = Q * K^T  (16 q x 128 k per wave)
            f32x4 sacc[8];
            #pragma unroll
            for (int n = 0; n < 8; n++) { f32x4 z = {0.f,0.f,0.f,0.f}; sacc[n] = z; }
            #pragma unroll
            for (int n = 0; n < 8; n++) {
                int row = n*16 + l15;
                #pragma unroll
                for (int ks = 0; ks < 4; ks++) {
                    short8 kf = *(const short8*)&Ks[row * 128 + FA_SW(ks*4 + quad, row) * 8];
                    sacc[n] = __builtin_amdgcn_mfma_f32_16x16x32_bf16(qf[ks], kf, sacc[n], 0, 0, 0);
                }
            }

            // ---- causal mask (only the last tile of the phase crosses the diag)
            if (j == n128 - 1) {
                int k0 = j * 128;
                #pragma unroll
                for (int n = 0; n < 8; n++)
                    #pragma unroll
                    for (int r = 0; r < 4; r++) {
                        int kcol = k0 + n*16 + l15;
                        int qrow = qt*64 + w*16 + quad*4 + r;
                        if (kcol > qrow) sacc[n][r] = -1e30f;
                    }
            }

            // ---- online softmax (row = quad*4+r; reduce over 16-lane group)
            #pragma unroll
            for (int r = 0; r < 4; r++) {
                float mx = sacc[0][r];
                #pragma unroll
                for (int n = 1; n < 8; n++) mx = fmaxf(mx, sacc[n][r]);
                mx = fmaxf(mx, __shfl_xor(mx, 1, 64));
                mx = fmaxf(mx, __shfl_xor(mx, 2, 64));
                mx = fmaxf(mx, __shfl_xor(mx, 4, 64));
                mx = fmaxf(mx, __shfl_xor(mx, 8, 64));
                float mnew = fmaxf(mrow[r], mx);
                float alpha = __expf(mrow[r] - mnew);
                mrow[r] = mnew;
                float s = 0.f;
                #pragma unroll
                for (int n = 0; n < 8; n++) {
                    float e = __expf(sacc[n][r] - mnew);
                    sacc[n][r] = e;
                    s += e;
                }
                s += __shfl_xor(s, 1, 64);
                s += __shfl_xor(s, 2, 64);
                s += __shfl_xor(s, 4, 64);
                s += __shfl_xor(s, 8, 64);
                lrow[r] = lrow[r] * alpha + s;
                #pragma unroll
                for (int n = 0; n < 8; n++) oacc[n][r] *= alpha;
            }

            __syncthreads();   // all waves done reading Ks before P overwrites

            // ---- P (bf16) -> Ks (swizzled), wave-private q band
            #pragma unroll
            for (int n = 0; n < 8; n++)
                #pragma unroll
                for (int r = 0; r < 4; r++) {
                    int qrow = w*16 + quad*4 + r;
                    int kcol = n*16 + l15;
                    Ks[qrow * 128 + FA_SW(kcol >> 3, qrow) * 8 + (kcol & 7)] = f2bf(sacc[n][r]);
                }

            // ---- O += P * V  (pf from own band — in-wave dependency only)
            short8 pf[4];
            #pragma unroll
            for (int ks = 0; ks < 4; ks++) {
                int row = w*16 + l15;
                pf[ks] = *(const short8*)&Ks[row * 128 + FA_SW(ks*4 + quad, row) * 8];
            }
            #pragma unroll
            for (int n = 0; n < 8; n++) {
                int row = n*16 + l15;
                #pragma unroll
                for (int ks = 0; ks < 4; ks++) {
                    short8 vf = *(const short8*)&Vs[row * 128 + FA_SW(ks*4 + quad, row) * 8];
                    oacc[n] = __builtin_amdgcn_mfma_f32_16x16x32_bf16(pf[ks], vf, oacc[n], 0, 0, 0);
                }
            }
        }

        // ---- epilogue for this phase
        float* Ob = O + ((size_t)(b * S_ + qt * 64)) * (H_*HD_) + (pair & 31) * HD_;
        #pragma unroll
        for (int r = 0; r < 4; r++) {
            float inv = 1.0f / lrow[r];
            int row = w*16 + quad*4 + r;
            #pragma unroll
            for (int n = 0; n < 8; n++)
                Ob[(size_t)row * (H_*HD_) + n*16 + l15] = oacc[n][r] * inv;
        }
    }
}

// ---------------------------------------------------------------------------
extern "C" void kernel_launch(void* const* d_in, const int* in_sizes, int n_in,
                              void* d_out, int out_size, void* d_ws, size_t ws_size,
                              hipStream_t stream)
{
    (void)in_sizes; (void)n_in; (void)out_size; (void)ws_size;
    const float* x    = (const float*)d_in[0];
    const float* cosb = (const float*)d_in[1];
    const float* sinb = (const float*)d_in[2];
    const int*   wq   = (const int*)d_in[3];
    const float* sq   = (const float*)d_in[4];
    const float* bq   = (const float*)d_in[5];
    const int*   wk   = (const int*)d_in[6];
    const float* sk   = (const float*)d_in[7];
    const float* bk   = (const float*)d_in[8];
    const int*   wv   = (const int*)d_in[9];
    const float* sv   = (const float*)d_in[10];
    const float* bv   = (const float*)d_in[11];
    const int*   wo   = (const int*)d_in[12];
    const float* so   = (const float*)d_in[13];
    float* out = (float*)d_out;
    char*  ws  = (char*)d_ws;

    // ws layout (~159.4 MB total)
    signed char*    Xi   = (signed char*)(ws + 0);              //  8.4 MB
    float*          Y    = (float*)(ws + 8388608ull);           // 50.3 MB
    signed char*    Wqkv = (signed char*)(ws + 58720256ull);    // 25.2 MB (Oi reuses)
    signed char*    Oi   = (signed char*)(ws + 58720256ull);
    signed char*    Wo   = (signed char*)(ws + 83886080ull);    // 16.8 MB
    unsigned short* Q    = (unsigned short*)(ws + 100663296ull);// 16.8 MB
    unsigned short* Kb   = (unsigned short*)(ws + 117440512ull);//  4.2 MB
    unsigned short* Vt   = (unsigned short*)(ws + 121634816ull);//  4.2 MB
    float*          O    = (float*)(ws + 125829120ull);         // 33.5 MB
    float*          sx   = (float*)(ws + 159383552ull);
    float*          sxo  = (float*)(ws + 159391744ull);

    // K1: quantize x rows -> int8 (K=4096)
    quantize_rows_k<<<dim3(NR), dim3(256), 0, stream>>>(x, Xi, sx);

    // K2: all weights -> int8, one launch
    convert_all_w<<<dim3(10240), dim3(256), 0, stream>>>(wq, wk, wv, wo, Wqkv, Wo);

    // K3: Y = Xi * Wqkv^T   (2048 x 6144, K=4096, int8 MFMA, BK=128 swizzled)
    gemm_i8_k<0><<<dim3(48,16,1), dim3(256), 0, stream>>>(
        Xi, Wqkv, Y, nullptr, nullptr, D_, D_, D_, NQKV);

    // K4: dequant + rope + pack (Q pre-scaled by 1/sqrt(HD))
    derope_k<<<dim3(NR), dim3(256), 0, stream>>>(
        Y, sx, sq, bq, sk, bk, sv, bv, cosb, sinb, Q, Kb, Vt);

    // K5: fused flash attention  (64 pairs x 8 balanced q-tile pairs)
    flash_attn_k<<<dim3(64, 8), dim3(256), 0, stream>>>(Q, Kb, Vt, O);

    // K6: quantize attention output rows -> int8 (K=4096)
    quantize_rows_k<<<dim3(NR), dim3(256), 0, stream>>>(O, Oi, sxo);

    // K7: out = float(Oi * Wo^T) * sxo[row] * so[col]  (int8 MFMA, BK=128)
    gemm_i8_k<3><<<dim3(32,16,1), dim3(256), 0, stream>>>(
        Oi, Wo, out, sxo, so, D_, D_, D_, D_);
}